// Round 12
// baseline (503.030 us; speedup 1.0000x reference)
//
#include <hip/hip_runtime.h>

typedef unsigned short u16;
typedef short s16x8 __attribute__((ext_vector_type(8)));
typedef float f32x4 __attribute__((ext_vector_type(4)));

#define SLOPE 0.01f
#define EPB 64

__device__ __forceinline__ float leaky(float x) { return x >= 0.f ? x : SLOPE * x; }

__device__ __forceinline__ u16 f2b(float f) {          // round-to-nearest-even
    union { float f; unsigned u; } v; v.f = f;
    unsigned r = v.u + 0x7FFFu + ((v.u >> 16) & 1u);
    return (u16)(r >> 16);
}
__device__ __forceinline__ float b2f(u16 b) {
    union { unsigned u; float f; } v; v.u = ((unsigned)b) << 16; return v.f;
}

// ---------------------------------------------------------------------------
// Init: edge part (deg histogram + recvf mark) and node part (tflag).
// ---------------------------------------------------------------------------
__global__ __launch_bounds__(256) void k_init(
    const int* __restrict__ src, const int* __restrict__ dst,
    const int* __restrict__ ntype, int* __restrict__ deg,
    float* __restrict__ recvf, int* __restrict__ tflag, int E, int N)
{
    int i = blockIdx.x * 256 + threadIdx.x;
    if (i < E) {
        if (ntype[src[i]] == 2) {
            int d = dst[i];
            atomicAdd(&deg[d], 1);
            recvf[d] = 1.0f;
        }
    } else {
        int j = i - E;
        if (j < N) tflag[j] = (ntype[j] == 2) ? 1 : 0;
    }
}

// ---------------------------------------------------------------------------
// Dual scan step 1: per-256-chunk sums.  y=0: deg->bsum, y=1: tflag->bsum2.
// ---------------------------------------------------------------------------
__global__ __launch_bounds__(256) void k_scan1(
    const int* __restrict__ deg, const int* __restrict__ tflag,
    int* __restrict__ bsum, int* __restrict__ bsum2, int n)
{
    __shared__ int s[256];
    const int* v = blockIdx.y ? tflag : deg;
    int* out = blockIdx.y ? bsum2 : bsum;
    int i = blockIdx.x * 256 + threadIdx.x;
    s[threadIdx.x] = (i < n) ? v[i] : 0;
    __syncthreads();
    for (int o = 128; o > 0; o >>= 1) {
        if (threadIdx.x < o) s[threadIdx.x] += s[threadIdx.x + o];
        __syncthreads();
    }
    if (threadIdx.x == 0) out[blockIdx.x] = s[0];
}

// ---------------------------------------------------------------------------
// Dual scan step 2: exclusive scan of block sums (nb <= 256) + total.
// ---------------------------------------------------------------------------
__global__ __launch_bounds__(256) void k_scan2(
    int* __restrict__ bsum, int* __restrict__ bsum2, int nb,
    int* __restrict__ cntp, int* __restrict__ tcntp)
{
    __shared__ int s[256];
    int* arr = blockIdx.x ? bsum2 : bsum;
    int* tot = blockIdx.x ? tcntp : cntp;
    int v = (threadIdx.x < nb) ? arr[threadIdx.x] : 0;
    s[threadIdx.x] = v;
    __syncthreads();
    for (int o = 1; o < 256; o <<= 1) {
        int x = (threadIdx.x >= o) ? s[threadIdx.x - o] : 0;
        __syncthreads();
        s[threadIdx.x] += x;
        __syncthreads();
    }
    if (threadIdx.x < nb) arr[threadIdx.x] = s[threadIdx.x] - v;  // exclusive
    if (threadIdx.x == 255) *tot = s[255];                        // total
}

// ---------------------------------------------------------------------------
// Dual scan step 3: per-element exclusive offsets.
// y=0: deg -> cursor.  y=1: tflag -> trank, and tlist[trank[i]] = i.
// ---------------------------------------------------------------------------
__global__ __launch_bounds__(256) void k_scan3(
    const int* __restrict__ deg, const int* __restrict__ tflag,
    const int* __restrict__ bsum, const int* __restrict__ bsum2,
    int* __restrict__ cursor, int* __restrict__ trank,
    int* __restrict__ tlist, int n)
{
    __shared__ int s[256];
    const int sel = blockIdx.y;
    const int* v = sel ? tflag : deg;
    const int* bexcl = sel ? bsum2 : bsum;
    int i = blockIdx.x * 256 + threadIdx.x;
    int x = (i < n) ? v[i] : 0;
    s[threadIdx.x] = x;
    __syncthreads();
    for (int o = 1; o < 256; o <<= 1) {
        int y = (threadIdx.x >= o) ? s[threadIdx.x - o] : 0;
        __syncthreads();
        s[threadIdx.x] += y;
        __syncthreads();
    }
    if (i < n) {
        int off = bexcl[blockIdx.x] + s[threadIdx.x] - x;
        if (sel) {
            trank[i] = off;
            if (x) tlist[off] = i;
        } else {
            cursor[i] = off;
        }
    }
}

// ---------------------------------------------------------------------------
// Scatter active edges into dst-sorted order via per-dst cursors.
// After this kernel, cursor[d] = END offset of d's segment (start = end-deg).
// ---------------------------------------------------------------------------
__global__ __launch_bounds__(256) void k_scatter_pos(
    const int* __restrict__ src, const int* __restrict__ dst,
    const int* __restrict__ ntype, const int* __restrict__ trank,
    int* __restrict__ cursor, int* __restrict__ eS,
    int* __restrict__ sSg, int E)
{
    int e = blockIdx.x * 256 + threadIdx.x;
    if (e < E) {
        int s = src[e];
        if (ntype[s] == 2) {
            int d = dst[e];
            int p = atomicAdd(&cursor[d], 1);
            eS[p] = e; sSg[p] = trank[s];
        }
    }
}

// ---------------------------------------------------------------------------
// One-time: gather ef rows into dst-sorted bf16 efS [cnt][64].
// ---------------------------------------------------------------------------
__global__ __launch_bounds__(256) void k_efgather(
    const float* __restrict__ ef, const int* __restrict__ eS,
    const int* __restrict__ cntp, u16* __restrict__ efS)
{
    const int cnt = *cntp;
    const int b0 = blockIdx.x * 64;
    if (b0 >= cnt) return;
    const int t = threadIdx.x;
    #pragma unroll
    for (int pz = 0; pz < 4; ++pz) {
        int idx = t + pz * 256;          // 1024 chunks = 64 edges x 16 float4
        int edge = idx >> 4, f4 = idx & 15;
        int p = b0 + edge;
        if (p < cnt) {
            float4 v = *(const float4*)(ef + (size_t)eS[p] * 64 + f4 * 4);
            ushort4 o;
            o.x = f2b(v.x); o.y = f2b(v.y); o.z = f2b(v.z); o.w = f2b(v.w);
            *(ushort4*)(efS + (size_t)p * 64 + f4 * 4) = o;
        }
    }
}

// ---------------------------------------------------------------------------
// Prep: nf -> bf16 (first n4 float4 chunks) + all weight transposes (tail).
// ---------------------------------------------------------------------------
__global__ __launch_bounds__(256) void k_prep(
    const float* __restrict__ nf, u16* __restrict__ hb0, int n4,
    const float* __restrict__ We0, const float* __restrict__ We1,
    const float* __restrict__ We2, const float* __restrict__ Wn0,
    const float* __restrict__ Wn1, const float* __restrict__ Wn2,
    u16* __restrict__ WTe, u16* __restrict__ WTn, u16* __restrict__ WTef)
{
    int i = blockIdx.x * 256 + threadIdx.x;
    if (i < n4) {
        float4 v = ((const float4*)nf)[i];
        ushort4 o;
        o.x = f2b(v.x); o.y = f2b(v.y); o.z = f2b(v.z); o.w = f2b(v.w);
        ((ushort4*)hb0)[i] = o;
        return;
    }
    int j = i - n4;
    if (j >= 3 * 73728) return;
    int l = j / 73728;
    int idx = j - l * 73728;
    const float* We = (l == 0) ? We0 : (l == 1) ? We1 : We2;
    const float* Wn = (l == 0) ? Wn0 : (l == 1) ? Wn1 : Wn2;
    if (idx < 32768) {
        int sel = idx >> 14, jj = idx & 16383;
        int k = jj >> 7, n = jj & 127;
        WTe[(size_t)l * 32768 + sel * 16384 + n * 128 + k] = f2b(We[sel * 16384 + jj]);
    } else if (idx < 65536) {
        int jj = idx - 32768;
        int k = jj >> 7, n = jj & 127;
        WTn[(size_t)l * 32768 + n * 256 + k] = f2b(Wn[jj]);
    } else {
        int jj = idx - 65536;
        int k = jj >> 7, n = jj & 127;
        WTef[(size_t)l * 8192 + n * 64 + k] = f2b(We[32768 + jj]);
    }
}

// ---------------------------------------------------------------------------
// MERGED per-layer producer: blocks [0, nT2) = Tsrc-half GEMM (task ranks),
// [nT2, 2*nT2) = Tdst-half GEMM (all nodes), [2*nT2, ...) = edge matvec
// msgS tiles.  LDS is a union of the two layouts.
// ---------------------------------------------------------------------------
__global__ __launch_bounds__(256) void k_T2msg(
    const u16* __restrict__ A, const u16* __restrict__ WTe_l,
    u16* __restrict__ Tsrc, u16* __restrict__ Tdst,
    const int* __restrict__ tlist, const int* __restrict__ tcntp,
    const u16* __restrict__ efS, const u16* __restrict__ WTef_l,
    const int* __restrict__ cntp, u16* __restrict__ msgS,
    int Nfull, int nT2)
{
    __shared__ u16 sh[2 * 128 * 72];     // 36.9 KB union
    const int t = threadIdx.x;
    const int bx = blockIdx.x;
    const int w = t >> 6, lane = t & 63;
    const int lo = lane & 15, q = lane >> 4;

    if (bx < 2 * nT2) {
        // ---------------- GEMM half ----------------
        u16 (*As)[72] = (u16(*)[72])sh;
        u16 (*Bs)[72] = (u16(*)[72])(sh + 128 * 72);
        const int sel = (bx >= nT2) ? 1 : 0;
        const int M = sel ? Nfull : *tcntp;
        const int m0 = (bx - sel * nT2) * 128;
        if (m0 >= M) return;
        const u16* WT = WTe_l + sel * 16384;
        u16* T = sel ? Tdst : Tsrc;
        const int wm = w >> 1, wn = w & 1;
        f32x4 acc[4][4] = {};

        const int row = t >> 1, koff = (t & 1) * 32;
        const int gm_s = m0 + row;
        int arow = gm_s;
        if (!sel && gm_s < M) arow = tlist[gm_s];

        for (int kt = 0; kt < 128; kt += 64) {
            #pragma unroll
            for (int j = 0; j < 4; ++j) {
                int4 va = make_int4(0, 0, 0, 0);
                if (gm_s < M) va = *(const int4*)(A + (size_t)arow * 128 + kt + koff + j * 8);
                *(int4*)&As[row][koff + j * 8] = va;
                *(int4*)&Bs[row][koff + j * 8] =
                    *(const int4*)(WT + (size_t)row * 128 + kt + koff + j * 8);
            }
            __syncthreads();
            #pragma unroll
            for (int kf = 0; kf < 2; ++kf) {
                s16x8 a[4], b[4];
                #pragma unroll
                for (int mi = 0; mi < 4; ++mi)
                    a[mi] = *(const s16x8*)&As[wm * 64 + mi * 16 + lo][kf * 32 + q * 8];
                #pragma unroll
                for (int ni = 0; ni < 4; ++ni)
                    b[ni] = *(const s16x8*)&Bs[wn * 64 + ni * 16 + lo][kf * 32 + q * 8];
                #pragma unroll
                for (int mi = 0; mi < 4; ++mi)
                    #pragma unroll
                    for (int ni = 0; ni < 4; ++ni)
                        acc[mi][ni] = __builtin_amdgcn_mfma_f32_16x16x32_bf16(
                            a[mi], b[ni], acc[mi][ni], 0, 0, 0);
            }
            __syncthreads();
        }
        const int lr = q * 4, lc = lo;
        #pragma unroll
        for (int mi = 0; mi < 4; ++mi) {
            #pragma unroll
            for (int r = 0; r < 4; ++r) {
                int gm = m0 + wm * 64 + mi * 16 + lr + r;
                if (gm < M) {
                    #pragma unroll
                    for (int ni = 0; ni < 4; ++ni)
                        T[(size_t)gm * 128 + wn * 64 + ni * 16 + lc] = f2b(acc[mi][ni][r]);
                }
            }
        }
    } else {
        // ---------------- edge matvec tile ----------------
        u16 (*Ms)[136] = (u16(*)[136])sh;
        const int cnt = *cntp;
        const int b0 = (bx - 2 * nT2) * EPB;
        if (b0 >= cnt) return;
        const int ei = w * 16 + lo;
        const int p = b0 + ei;

        f32x4 acc[8] = {};
        #pragma unroll
        for (int kf = 0; kf < 2; ++kf) {
            s16x8 b = {};
            if (p < cnt) b = *(const s16x8*)(efS + (size_t)p * 64 + kf * 32 + q * 8);
            #pragma unroll
            for (int mi = 0; mi < 8; ++mi) {
                s16x8 a = *(const s16x8*)(WTef_l + (size_t)(mi * 16 + lo) * 64 + kf * 32 + q * 8);
                acc[mi] = __builtin_amdgcn_mfma_f32_16x16x32_bf16(a, b, acc[mi], 0, 0, 0);
            }
        }
        // D mapping: col=lane&15 (edge), row = mi*16 + q*4 + r (feature n)
        #pragma unroll
        for (int mi = 0; mi < 8; ++mi) {
            ushort4 o;
            o.x = f2b(acc[mi][0]); o.y = f2b(acc[mi][1]);
            o.z = f2b(acc[mi][2]); o.w = f2b(acc[mi][3]);
            *(ushort4*)&Ms[ei][mi * 16 + q * 4] = o;
        }
        __syncthreads();
        #pragma unroll
        for (int pz = 0; pz < 4; ++pz) {
            int idx = t + pz * 256;
            int rrow = idx >> 4, c8 = idx & 15;
            int pp = b0 + rrow;
            if (pp < cnt)
                *(int4*)(msgS + (size_t)pp * 128 + c8 * 8) = *(const int4*)&Ms[rrow][c8 * 8];
        }
    }
}

// ---------------------------------------------------------------------------
// FUSED node kernel: phase 1 = CSR segmented reduce of this block's 128 nodes
// into LDS Rs (no atomics, coalesced msgS stream since edges are dst-sorted);
// phase 2 = out = leaky([H | Rs] @ Wn) * recv.
// ---------------------------------------------------------------------------
__global__ __launch_bounds__(256) void k_node_fused(
    const u16* __restrict__ H, const u16* __restrict__ msgS,
    const u16* __restrict__ Tsrc, const u16* __restrict__ Tdst,
    const int* __restrict__ sSg, const int* __restrict__ deg,
    const int* __restrict__ segEnd, const u16* __restrict__ WT,
    const float* __restrict__ recvf, u16* __restrict__ O16,
    float* __restrict__ O32, int fin, int M)
{
    __shared__ u16 As[128][72];
    __shared__ u16 Bs[128][72];
    __shared__ u16 Rs[128][136];
    const int t = threadIdx.x;
    const int m0 = blockIdx.x * 128;
    const int w = t >> 6, lane = t & 63;
    const int lo = lane & 15, q = lane >> 4;

    // ---- phase 1: reduce nodes m0+w*32 .. m0+w*32+31 (one wave each) ----
    for (int k = 0; k < 32; ++k) {
        int rrow = w * 32 + k;
        int d = m0 + rrow;
        if (d >= M) break;
        unsigned outw = 0;
        int dg = deg[d];
        if (dg > 0) {
            int end = segEnd[d], beg = end - dg;
            unsigned td = *(const unsigned*)(Tdst + (size_t)d * 128 + lane * 2);
            float td0 = b2f((u16)(td & 0xffff)), td1 = b2f((u16)(td >> 16));
            float a0 = 0.f, a1 = 0.f;
            for (int i = beg; i < end; ++i) {
                int s = sSg[i];          // wave-uniform -> broadcast
                unsigned m  = *(const unsigned*)(msgS + (size_t)i * 128 + lane * 2);
                unsigned ts = *(const unsigned*)(Tsrc + (size_t)s * 128 + lane * 2);
                a0 += leaky(b2f((u16)(m & 0xffff)) + b2f((u16)(ts & 0xffff)) + td0);
                a1 += leaky(b2f((u16)(m >> 16))    + b2f((u16)(ts >> 16))    + td1);
            }
            outw = (unsigned)f2b(a0) | ((unsigned)f2b(a1) << 16);
        }
        *(unsigned*)&Rs[rrow][lane * 2] = outw;
    }
    __syncthreads();

    // ---- phase 2: GEMM [H | Rs] @ WT ----
    const int wm = w >> 1, wn = w & 1;
    f32x4 acc[4][4] = {};
    const int row = t >> 1, koff = (t & 1) * 32;
    const int gm_s = m0 + row;

    for (int kt = 0; kt < 256; kt += 64) {
        if (kt < 128) {
            #pragma unroll
            for (int j = 0; j < 4; ++j) {
                int4 va = make_int4(0, 0, 0, 0);
                if (gm_s < M) va = *(const int4*)(H + (size_t)gm_s * 128 + kt + koff + j * 8);
                *(int4*)&As[row][koff + j * 8] = va;
            }
        }
        #pragma unroll
        for (int j = 0; j < 4; ++j)
            *(int4*)&Bs[row][koff + j * 8] =
                *(const int4*)(WT + (size_t)row * 256 + kt + koff + j * 8);
        __syncthreads();
        #pragma unroll
        for (int kf = 0; kf < 2; ++kf) {
            s16x8 a[4], b[4];
            #pragma unroll
            for (int mi = 0; mi < 4; ++mi) {
                if (kt < 128)
                    a[mi] = *(const s16x8*)&As[wm * 64 + mi * 16 + lo][kf * 32 + q * 8];
                else
                    a[mi] = *(const s16x8*)&Rs[wm * 64 + mi * 16 + lo][(kt - 128) + kf * 32 + q * 8];
            }
            #pragma unroll
            for (int ni = 0; ni < 4; ++ni)
                b[ni] = *(const s16x8*)&Bs[wn * 64 + ni * 16 + lo][kf * 32 + q * 8];
            #pragma unroll
            for (int mi = 0; mi < 4; ++mi)
                #pragma unroll
                for (int ni = 0; ni < 4; ++ni)
                    acc[mi][ni] = __builtin_amdgcn_mfma_f32_16x16x32_bf16(
                        a[mi], b[ni], acc[mi][ni], 0, 0, 0);
        }
        __syncthreads();
    }
    const int lr = q * 4, lc = lo;
    #pragma unroll
    for (int mi = 0; mi < 4; ++mi) {
        #pragma unroll
        for (int r = 0; r < 4; ++r) {
            int gm = m0 + wm * 64 + mi * 16 + lr + r;
            if (gm < M) {
                float rv = recvf[gm];
                #pragma unroll
                for (int ni = 0; ni < 4; ++ni) {
                    float val = leaky(acc[mi][ni][r]) * rv;
                    size_t o = (size_t)gm * 128 + wn * 64 + ni * 16 + lc;
                    if (fin) O32[o] = val;
                    else     O16[o] = f2b(val);
                }
            }
        }
    }
}

// ---------------------------------------------------------------------------
extern "C" void kernel_launch(void* const* d_in, const int* in_sizes, int n_in,
                              void* d_out, int out_size, void* d_ws, size_t ws_size,
                              hipStream_t stream)
{
    const float* nf    = (const float*)d_in[0];
    const float* ef    = (const float*)d_in[1];
    const int*   src   = (const int*)d_in[2];
    const int*   dst   = (const int*)d_in[3];
    const int*   ntype = (const int*)d_in[4];
    const float* We[3] = {(const float*)d_in[5], (const float*)d_in[7], (const float*)d_in[9]};
    const float* Wn[3] = {(const float*)d_in[6], (const float*)d_in[8], (const float*)d_in[10]};

    const int N = in_sizes[0] / 128;
    const int E = in_sizes[1] / 64;

    u16* Tsrc = (u16*)d_ws;                        // N*128 (only *tcnt used)
    u16* Tdst = Tsrc + (size_t)N * 128;            // N*128
    u16* hb0  = Tdst + (size_t)N * 128;            // N*128
    u16* hb1  = hb0 + (size_t)N * 128;             // N*128
    u16* WTe  = hb1 + (size_t)N * 128;             // 3*32768
    u16* WTn  = WTe + 3 * 32768;                   // 3*32768
    u16* WTef = WTn + 3 * 32768;                   // 3*8192
    u16* efS  = WTef + 3 * 8192;                   // E*64 (only cnt*64 used)
    u16* msgS = efS + (size_t)E * 64;              // E*128 (only cnt*128 used)
    float* recvf = (float*)(msgS + (size_t)E * 128); // N  } zeroed together
    int* deg    = (int*)(recvf + N);               // N    }
    int* cursor = deg + N;                         // N (becomes segment END)
    int* tflag  = cursor + N;                      // N
    int* trank  = tflag + N;                       // N
    int* tlist  = trank + N;                       // N
    int* bsum   = tlist + N;                       // 256
    int* bsum2  = bsum + 256;                      // 256
    int* cntp   = bsum2 + 256;                     // 1 (+pad)
    int* tcntp  = cntp + 4;                        // 1 (+pad)
    int* eS     = tcntp + 4;                       // E
    int* sSg    = eS + E;                          // E

    const int nb  = (N + 255) / 256;               // 196 <= 256 ok
    const int gEb = (E + 255) / 256;
    const int n4  = N * 128 / 4;
    const int nT2 = (N + 127) / 128;
    const int gM  = (E + EPB - 1) / EPB;

    hipMemsetAsync(recvf, 0, (size_t)N * 2 * sizeof(float), stream);

    k_init<<<(E + N + 255) / 256, 256, 0, stream>>>(src, dst, ntype, deg, recvf, tflag, E, N);
    k_scan1<<<dim3(nb, 2), 256, 0, stream>>>(deg, tflag, bsum, bsum2, N);
    k_scan2<<<2, 256, 0, stream>>>(bsum, bsum2, nb, cntp, tcntp);
    k_scan3<<<dim3(nb, 2), 256, 0, stream>>>(deg, tflag, bsum, bsum2, cursor, trank, tlist, N);
    k_scatter_pos<<<gEb, 256, 0, stream>>>(src, dst, ntype, trank, cursor, eS, sSg, E);
    k_efgather<<<(E + 63) / 64, 256, 0, stream>>>(ef, eS, cntp, efS);
    k_prep<<<(n4 + 3 * 73728 + 255) / 256, 256, 0, stream>>>(
        nf, hb0, n4, We[0], We[1], We[2], Wn[0], Wn[1], Wn[2], WTe, WTn, WTef);

    const u16* hIn[3]  = {hb0, hb1, hb0};
    u16*       hOut[3] = {hb1, hb0, hb1};
    for (int l = 0; l < 3; ++l) {
        int fin = (l == 2);
        k_T2msg<<<2 * nT2 + gM, 256, 0, stream>>>(
            hIn[l], WTe + (size_t)l * 32768, Tsrc, Tdst, tlist, tcntp,
            efS, WTef + (size_t)l * 8192, cntp, msgS, N, nT2);
        k_node_fused<<<nT2, 256, 0, stream>>>(
            hIn[l], msgS, Tsrc, Tdst, sSg, deg, cursor,
            WTn + (size_t)l * 32768, recvf, hOut[l], (float*)d_out, fin, N);
    }
}

// Round 13
// 327.309 us; speedup vs baseline: 1.5369x; 1.5369x over previous
//
#include <hip/hip_runtime.h>

typedef unsigned short u16;
typedef short s16x8 __attribute__((ext_vector_type(8)));
typedef float f32x4 __attribute__((ext_vector_type(4)));

#define SLOPE 0.01f
#define EPB 64

__device__ __forceinline__ float leaky(float x) { return x >= 0.f ? x : SLOPE * x; }

__device__ __forceinline__ u16 f2b(float f) {          // round-to-nearest-even
    union { float f; unsigned u; } v; v.f = f;
    unsigned r = v.u + 0x7FFFu + ((v.u >> 16) & 1u);
    return (u16)(r >> 16);
}
__device__ __forceinline__ float b2f(u16 b) {
    union { unsigned u; float f; } v; v.u = ((unsigned)b) << 16; return v.f;
}

// ---------------------------------------------------------------------------
// Init: edge part (deg histogram + recvf mark) and node part (tflag).
// ---------------------------------------------------------------------------
__global__ __launch_bounds__(256) void k_init(
    const int* __restrict__ src, const int* __restrict__ dst,
    const int* __restrict__ ntype, int* __restrict__ deg,
    float* __restrict__ recvf, int* __restrict__ tflag, int E, int N)
{
    int i = blockIdx.x * 256 + threadIdx.x;
    if (i < E) {
        if (ntype[src[i]] == 2) {
            int d = dst[i];
            atomicAdd(&deg[d], 1);
            recvf[d] = 1.0f;
        }
    } else {
        int j = i - E;
        if (j < N) tflag[j] = (ntype[j] == 2) ? 1 : 0;
    }
}

// ---------------------------------------------------------------------------
// Dual scan step 1: per-256-chunk sums.  y=0: deg->bsum, y=1: tflag->bsum2.
// ---------------------------------------------------------------------------
__global__ __launch_bounds__(256) void k_scan1(
    const int* __restrict__ deg, const int* __restrict__ tflag,
    int* __restrict__ bsum, int* __restrict__ bsum2, int n)
{
    __shared__ int s[256];
    const int* v = blockIdx.y ? tflag : deg;
    int* out = blockIdx.y ? bsum2 : bsum;
    int i = blockIdx.x * 256 + threadIdx.x;
    s[threadIdx.x] = (i < n) ? v[i] : 0;
    __syncthreads();
    for (int o = 128; o > 0; o >>= 1) {
        if (threadIdx.x < o) s[threadIdx.x] += s[threadIdx.x + o];
        __syncthreads();
    }
    if (threadIdx.x == 0) out[blockIdx.x] = s[0];
}

// ---------------------------------------------------------------------------
// Dual scan step 2: exclusive scan of block sums (nb <= 256) + total.
// ---------------------------------------------------------------------------
__global__ __launch_bounds__(256) void k_scan2(
    int* __restrict__ bsum, int* __restrict__ bsum2, int nb,
    int* __restrict__ cntp, int* __restrict__ tcntp)
{
    __shared__ int s[256];
    int* arr = blockIdx.x ? bsum2 : bsum;
    int* tot = blockIdx.x ? tcntp : cntp;
    int v = (threadIdx.x < nb) ? arr[threadIdx.x] : 0;
    s[threadIdx.x] = v;
    __syncthreads();
    for (int o = 1; o < 256; o <<= 1) {
        int x = (threadIdx.x >= o) ? s[threadIdx.x - o] : 0;
        __syncthreads();
        s[threadIdx.x] += x;
        __syncthreads();
    }
    if (threadIdx.x < nb) arr[threadIdx.x] = s[threadIdx.x] - v;  // exclusive
    if (threadIdx.x == 255) *tot = s[255];                        // total
}

// ---------------------------------------------------------------------------
// Dual scan step 3: per-element exclusive offsets.
// y=0: deg -> cursor.  y=1: tflag -> trank, and tlist[trank[i]] = i.
// ---------------------------------------------------------------------------
__global__ __launch_bounds__(256) void k_scan3(
    const int* __restrict__ deg, const int* __restrict__ tflag,
    const int* __restrict__ bsum, const int* __restrict__ bsum2,
    int* __restrict__ cursor, int* __restrict__ trank,
    int* __restrict__ tlist, int n)
{
    __shared__ int s[256];
    const int sel = blockIdx.y;
    const int* v = sel ? tflag : deg;
    const int* bexcl = sel ? bsum2 : bsum;
    int i = blockIdx.x * 256 + threadIdx.x;
    int x = (i < n) ? v[i] : 0;
    s[threadIdx.x] = x;
    __syncthreads();
    for (int o = 1; o < 256; o <<= 1) {
        int y = (threadIdx.x >= o) ? s[threadIdx.x - o] : 0;
        __syncthreads();
        s[threadIdx.x] += y;
        __syncthreads();
    }
    if (i < n) {
        int off = bexcl[blockIdx.x] + s[threadIdx.x] - x;
        if (sel) {
            trank[i] = off;
            if (x) tlist[off] = i;
        } else {
            cursor[i] = off;
        }
    }
}

// ---------------------------------------------------------------------------
// Scatter active edges into dst-sorted order via per-dst cursors.
// After this kernel, cursor[d] = END offset of d's segment (start = end-deg).
// ---------------------------------------------------------------------------
__global__ __launch_bounds__(256) void k_scatter_pos(
    const int* __restrict__ src, const int* __restrict__ dst,
    const int* __restrict__ ntype, const int* __restrict__ trank,
    int* __restrict__ cursor, int* __restrict__ eS,
    int* __restrict__ sSg, int E)
{
    int e = blockIdx.x * 256 + threadIdx.x;
    if (e < E) {
        int s = src[e];
        if (ntype[s] == 2) {
            int d = dst[e];
            int p = atomicAdd(&cursor[d], 1);
            eS[p] = e; sSg[p] = trank[s];
        }
    }
}

// ---------------------------------------------------------------------------
// Prep (merged): [0, n4)           nf -> bf16
//                [n4, n4+221184)   weight transposes (3 layers)
//                [.., .. + E*16)   efgather: one float4 chunk per thread
// ---------------------------------------------------------------------------
__global__ __launch_bounds__(256) void k_prep(
    const float* __restrict__ nf, u16* __restrict__ hb0, int n4,
    const float* __restrict__ We0, const float* __restrict__ We1,
    const float* __restrict__ We2, const float* __restrict__ Wn0,
    const float* __restrict__ Wn1, const float* __restrict__ Wn2,
    u16* __restrict__ WTe, u16* __restrict__ WTn, u16* __restrict__ WTef,
    const float* __restrict__ ef, const int* __restrict__ eS,
    const int* __restrict__ cntp, u16* __restrict__ efS, int E)
{
    int i = blockIdx.x * 256 + threadIdx.x;
    if (i < n4) {
        float4 v = ((const float4*)nf)[i];
        ushort4 o;
        o.x = f2b(v.x); o.y = f2b(v.y); o.z = f2b(v.z); o.w = f2b(v.w);
        ((ushort4*)hb0)[i] = o;
        return;
    }
    int j = i - n4;
    if (j < 3 * 73728) {
        int l = j / 73728;
        int idx = j - l * 73728;
        const float* We = (l == 0) ? We0 : (l == 1) ? We1 : We2;
        const float* Wn = (l == 0) ? Wn0 : (l == 1) ? Wn1 : Wn2;
        if (idx < 32768) {
            int sel = idx >> 14, jj = idx & 16383;
            int k = jj >> 7, n = jj & 127;
            WTe[(size_t)l * 32768 + sel * 16384 + n * 128 + k] = f2b(We[sel * 16384 + jj]);
        } else if (idx < 65536) {
            int jj = idx - 32768;
            int k = jj >> 7, n = jj & 127;
            WTn[(size_t)l * 32768 + n * 256 + k] = f2b(Wn[jj]);
        } else {
            int jj = idx - 65536;
            int k = jj >> 7, n = jj & 127;
            WTef[(size_t)l * 8192 + n * 64 + k] = f2b(We[32768 + jj]);
        }
        return;
    }
    int g = j - 3 * 73728;               // efgather chunk id
    if (g >= E * 16) return;
    int p = g >> 4, f4 = g & 15;
    if (p < *cntp) {
        float4 v = *(const float4*)(ef + (size_t)eS[p] * 64 + f4 * 4);
        ushort4 o;
        o.x = f2b(v.x); o.y = f2b(v.y); o.z = f2b(v.z); o.w = f2b(v.w);
        *(ushort4*)(efS + (size_t)p * 64 + f4 * 4) = o;
    }
}

// ---------------------------------------------------------------------------
// MERGED per-layer producer: blocks [0, nT2) = Tsrc-half GEMM (task ranks),
// [nT2, 2*nT2) = Tdst-half GEMM (all nodes), [2*nT2, ...) = edge matvec
// msgS tiles.  LDS is a union of the two layouts.
// ---------------------------------------------------------------------------
__global__ __launch_bounds__(256) void k_T2msg(
    const u16* __restrict__ A, const u16* __restrict__ WTe_l,
    u16* __restrict__ Tsrc, u16* __restrict__ Tdst,
    const int* __restrict__ tlist, const int* __restrict__ tcntp,
    const u16* __restrict__ efS, const u16* __restrict__ WTef_l,
    const int* __restrict__ cntp, u16* __restrict__ msgS,
    int Nfull, int nT2)
{
    __shared__ u16 sh[2 * 128 * 72];     // 36.9 KB union
    const int t = threadIdx.x;
    const int bx = blockIdx.x;
    const int w = t >> 6, lane = t & 63;
    const int lo = lane & 15, q = lane >> 4;

    if (bx < 2 * nT2) {
        // ---------------- GEMM half ----------------
        u16 (*As)[72] = (u16(*)[72])sh;
        u16 (*Bs)[72] = (u16(*)[72])(sh + 128 * 72);
        const int sel = (bx >= nT2) ? 1 : 0;
        const int M = sel ? Nfull : *tcntp;
        const int m0 = (bx - sel * nT2) * 128;
        if (m0 >= M) return;
        const u16* WT = WTe_l + sel * 16384;
        u16* T = sel ? Tdst : Tsrc;
        const int wm = w >> 1, wn = w & 1;
        f32x4 acc[4][4] = {};

        const int row = t >> 1, koff = (t & 1) * 32;
        const int gm_s = m0 + row;
        int arow = gm_s;
        if (!sel && gm_s < M) arow = tlist[gm_s];

        for (int kt = 0; kt < 128; kt += 64) {
            #pragma unroll
            for (int j = 0; j < 4; ++j) {
                int4 va = make_int4(0, 0, 0, 0);
                if (gm_s < M) va = *(const int4*)(A + (size_t)arow * 128 + kt + koff + j * 8);
                *(int4*)&As[row][koff + j * 8] = va;
                *(int4*)&Bs[row][koff + j * 8] =
                    *(const int4*)(WT + (size_t)row * 128 + kt + koff + j * 8);
            }
            __syncthreads();
            #pragma unroll
            for (int kf = 0; kf < 2; ++kf) {
                s16x8 a[4], b[4];
                #pragma unroll
                for (int mi = 0; mi < 4; ++mi)
                    a[mi] = *(const s16x8*)&As[wm * 64 + mi * 16 + lo][kf * 32 + q * 8];
                #pragma unroll
                for (int ni = 0; ni < 4; ++ni)
                    b[ni] = *(const s16x8*)&Bs[wn * 64 + ni * 16 + lo][kf * 32 + q * 8];
                #pragma unroll
                for (int mi = 0; mi < 4; ++mi)
                    #pragma unroll
                    for (int ni = 0; ni < 4; ++ni)
                        acc[mi][ni] = __builtin_amdgcn_mfma_f32_16x16x32_bf16(
                            a[mi], b[ni], acc[mi][ni], 0, 0, 0);
            }
            __syncthreads();
        }
        const int lr = q * 4, lc = lo;
        #pragma unroll
        for (int mi = 0; mi < 4; ++mi) {
            #pragma unroll
            for (int r = 0; r < 4; ++r) {
                int gm = m0 + wm * 64 + mi * 16 + lr + r;
                if (gm < M) {
                    #pragma unroll
                    for (int ni = 0; ni < 4; ++ni)
                        T[(size_t)gm * 128 + wn * 64 + ni * 16 + lc] = f2b(acc[mi][ni][r]);
                }
            }
        }
    } else {
        // ---------------- edge matvec tile ----------------
        u16 (*Ms)[136] = (u16(*)[136])sh;
        const int cnt = *cntp;
        const int b0 = (bx - 2 * nT2) * EPB;
        if (b0 >= cnt) return;
        const int ei = w * 16 + lo;
        const int p = b0 + ei;

        f32x4 acc[8] = {};
        #pragma unroll
        for (int kf = 0; kf < 2; ++kf) {
            s16x8 b = {};
            if (p < cnt) b = *(const s16x8*)(efS + (size_t)p * 64 + kf * 32 + q * 8);
            #pragma unroll
            for (int mi = 0; mi < 8; ++mi) {
                s16x8 a = *(const s16x8*)(WTef_l + (size_t)(mi * 16 + lo) * 64 + kf * 32 + q * 8);
                acc[mi] = __builtin_amdgcn_mfma_f32_16x16x32_bf16(a, b, acc[mi], 0, 0, 0);
            }
        }
        // D mapping: col=lane&15 (edge), row = mi*16 + q*4 + r (feature n)
        #pragma unroll
        for (int mi = 0; mi < 8; ++mi) {
            ushort4 o;
            o.x = f2b(acc[mi][0]); o.y = f2b(acc[mi][1]);
            o.z = f2b(acc[mi][2]); o.w = f2b(acc[mi][3]);
            *(ushort4*)&Ms[ei][mi * 16 + q * 4] = o;
        }
        __syncthreads();
        #pragma unroll
        for (int pz = 0; pz < 4; ++pz) {
            int idx = t + pz * 256;
            int rrow = idx >> 4, c8 = idx & 15;
            int pp = b0 + rrow;
            if (pp < cnt)
                *(int4*)(msgS + (size_t)pp * 128 + c8 * 8) = *(const int4*)&Ms[rrow][c8 * 8];
        }
    }
}

// ---------------------------------------------------------------------------
// CSR segmented reduce: one wave per dst node, NO atomics, plain bf16 store.
//   red[d] = sum_{i in seg(d)} leaky(msg[i] + Tsrc[sSg[i]] + Tdst[d])
// ---------------------------------------------------------------------------
__global__ __launch_bounds__(256) void k_reduce(
    const u16* __restrict__ msgS, const u16* __restrict__ Tsrc,
    const u16* __restrict__ Tdst, const int* __restrict__ sSg,
    const int* __restrict__ deg, const int* __restrict__ segEnd,
    u16* __restrict__ redb, int N)
{
    const int w = threadIdx.x >> 6, lane = threadIdx.x & 63;
    const int d = blockIdx.x * 4 + w;
    if (d >= N) return;
    const int dg = deg[d];
    if (dg == 0) return;                 // recv=0 masks these rows downstream
    const int end = segEnd[d], beg = end - dg;

    unsigned td = *(const unsigned*)(Tdst + (size_t)d * 128 + lane * 2);
    const float td0 = b2f((u16)(td & 0xffff)), td1 = b2f((u16)(td >> 16));
    float a0 = 0.f, a1 = 0.f;
    for (int i = beg; i < end; ++i) {
        int s = sSg[i];                  // uniform across wave -> broadcast
        unsigned m  = *(const unsigned*)(msgS + (size_t)i * 128 + lane * 2);
        unsigned ts = *(const unsigned*)(Tsrc + (size_t)s * 128 + lane * 2);
        a0 += leaky(b2f((u16)(m & 0xffff)) + b2f((u16)(ts & 0xffff)) + td0);
        a1 += leaky(b2f((u16)(m >> 16))    + b2f((u16)(ts >> 16))    + td1);
    }
    unsigned out = (unsigned)f2b(a0) | ((unsigned)f2b(a1) << 16);
    *(unsigned*)(redb + (size_t)d * 128 + lane * 2) = out;
}

// ---------------------------------------------------------------------------
// out = leaky([H | R] @ Wn) * recv.  H and R both bf16 [M][128].
// ---------------------------------------------------------------------------
__global__ __launch_bounds__(256) void k_gemm_node(
    const u16* __restrict__ H, const u16* __restrict__ R,
    const u16* __restrict__ WT, const float* __restrict__ recvf,
    u16* __restrict__ O16, float* __restrict__ O32, int fin, int M)
{
    __shared__ u16 As[128][72];
    __shared__ u16 Bs[128][72];
    const int t = threadIdx.x;
    const int m0 = blockIdx.x * 128;
    const int w = t >> 6, lane = t & 63, wm = w >> 1, wn = w & 1;
    f32x4 acc[4][4] = {};

    const int row = t >> 1, koff = (t & 1) * 32;
    const int gm_s = m0 + row;

    for (int kt = 0; kt < 256; kt += 64) {
        const u16* Ap = (kt < 128) ? (H + kt) : (R + (kt - 128));
        #pragma unroll
        for (int j = 0; j < 4; ++j) {
            int4 va = make_int4(0, 0, 0, 0);
            if (gm_s < M) va = *(const int4*)(Ap + (size_t)gm_s * 128 + koff + j * 8);
            *(int4*)&As[row][koff + j * 8] = va;
            *(int4*)&Bs[row][koff + j * 8] =
                *(const int4*)(WT + (size_t)row * 256 + kt + koff + j * 8);
        }
        __syncthreads();
        #pragma unroll
        for (int kf = 0; kf < 2; ++kf) {
            s16x8 a[4], b[4];
            #pragma unroll
            for (int mi = 0; mi < 4; ++mi)
                a[mi] = *(const s16x8*)&As[wm * 64 + mi * 16 + (lane & 15)][kf * 32 + (lane >> 4) * 8];
            #pragma unroll
            for (int ni = 0; ni < 4; ++ni)
                b[ni] = *(const s16x8*)&Bs[wn * 64 + ni * 16 + (lane & 15)][kf * 32 + (lane >> 4) * 8];
            #pragma unroll
            for (int mi = 0; mi < 4; ++mi)
                #pragma unroll
                for (int ni = 0; ni < 4; ++ni)
                    acc[mi][ni] = __builtin_amdgcn_mfma_f32_16x16x32_bf16(
                        a[mi], b[ni], acc[mi][ni], 0, 0, 0);
        }
        __syncthreads();
    }
    const int lr = (lane >> 4) * 4, lc = lane & 15;
    #pragma unroll
    for (int mi = 0; mi < 4; ++mi) {
        #pragma unroll
        for (int r = 0; r < 4; ++r) {
            int gm = m0 + wm * 64 + mi * 16 + lr + r;
            if (gm < M) {
                float rv = recvf[gm];
                #pragma unroll
                for (int ni = 0; ni < 4; ++ni) {
                    float val = leaky(acc[mi][ni][r]) * rv;
                    size_t o = (size_t)gm * 128 + wn * 64 + ni * 16 + lc;
                    if (fin) O32[o] = val;
                    else     O16[o] = f2b(val);
                }
            }
        }
    }
}

// ---------------------------------------------------------------------------
extern "C" void kernel_launch(void* const* d_in, const int* in_sizes, int n_in,
                              void* d_out, int out_size, void* d_ws, size_t ws_size,
                              hipStream_t stream)
{
    const float* nf    = (const float*)d_in[0];
    const float* ef    = (const float*)d_in[1];
    const int*   src   = (const int*)d_in[2];
    const int*   dst   = (const int*)d_in[3];
    const int*   ntype = (const int*)d_in[4];
    const float* We[3] = {(const float*)d_in[5], (const float*)d_in[7], (const float*)d_in[9]};
    const float* Wn[3] = {(const float*)d_in[6], (const float*)d_in[8], (const float*)d_in[10]};

    const int N = in_sizes[0] / 128;
    const int E = in_sizes[1] / 64;

    u16* Tsrc = (u16*)d_ws;                        // N*128 (only *tcnt used)
    u16* Tdst = Tsrc + (size_t)N * 128;            // N*128
    u16* hb0  = Tdst + (size_t)N * 128;            // N*128
    u16* hb1  = hb0 + (size_t)N * 128;             // N*128
    u16* redb = hb1 + (size_t)N * 128;             // N*128 bf16
    u16* WTe  = redb + (size_t)N * 128;            // 3*32768
    u16* WTn  = WTe + 3 * 32768;                   // 3*32768
    u16* WTef = WTn + 3 * 32768;                   // 3*8192
    u16* efS  = WTef + 3 * 8192;                   // E*64 (only cnt*64 used)
    u16* msgS = efS + (size_t)E * 64;              // E*128 (only cnt*128 used)
    float* recvf = (float*)(msgS + (size_t)E * 128); // N  } zeroed together
    int* deg    = (int*)(recvf + N);               // N    }
    int* cursor = deg + N;                         // N (becomes segment END)
    int* tflag  = cursor + N;                      // N
    int* trank  = tflag + N;                       // N
    int* tlist  = trank + N;                       // N
    int* bsum   = tlist + N;                       // 256
    int* bsum2  = bsum + 256;                      // 256
    int* cntp   = bsum2 + 256;                     // 1 (+pad)
    int* tcntp  = cntp + 4;                        // 1 (+pad)
    int* eS     = tcntp + 4;                       // E
    int* sSg    = eS + E;                          // E

    const int nb  = (N + 255) / 256;               // 196 <= 256 ok
    const int gEb = (E + 255) / 256;
    const int n4  = N * 128 / 4;
    const int nT2 = (N + 127) / 128;
    const int gM  = (E + EPB - 1) / EPB;
    const int prepWork = n4 + 3 * 73728 + E * 16;

    hipMemsetAsync(recvf, 0, (size_t)N * 2 * sizeof(float), stream);

    k_init<<<(E + N + 255) / 256, 256, 0, stream>>>(src, dst, ntype, deg, recvf, tflag, E, N);
    k_scan1<<<dim3(nb, 2), 256, 0, stream>>>(deg, tflag, bsum, bsum2, N);
    k_scan2<<<2, 256, 0, stream>>>(bsum, bsum2, nb, cntp, tcntp);
    k_scan3<<<dim3(nb, 2), 256, 0, stream>>>(deg, tflag, bsum, bsum2, cursor, trank, tlist, N);
    k_scatter_pos<<<gEb, 256, 0, stream>>>(src, dst, ntype, trank, cursor, eS, sSg, E);
    k_prep<<<(prepWork + 255) / 256, 256, 0, stream>>>(
        nf, hb0, n4, We[0], We[1], We[2], Wn[0], Wn[1], Wn[2], WTe, WTn, WTef,
        ef, eS, cntp, efS, E);

    dim3 gG((N + 127) / 128);
    int  gR = (N + 3) / 4;

    const u16* hIn[3]  = {hb0, hb1, hb0};
    u16*       hOut[3] = {hb1, hb0, hb1};
    for (int l = 0; l < 3; ++l) {
        int fin = (l == 2);
        k_T2msg<<<2 * nT2 + gM, 256, 0, stream>>>(
            hIn[l], WTe + (size_t)l * 32768, Tsrc, Tdst, tlist, tcntp,
            efS, WTef + (size_t)l * 8192, cntp, msgS, N, nT2);
        k_reduce<<<gR, 256, 0, stream>>>(msgS, Tsrc, Tdst, sSg, deg, cursor, redb, N);
        k_gemm_node<<<gG, 256, 0, stream>>>(hIn[l], redb, WTn + (size_t)l * 32768,
                                            recvf, hOut[l], (float*)d_out, fin, N);
    }
}

// Round 14
// 315.919 us; speedup vs baseline: 1.5923x; 1.0361x over previous
//
#include <hip/hip_runtime.h>

typedef unsigned short u16;
typedef short s16x8 __attribute__((ext_vector_type(8)));
typedef float f32x4 __attribute__((ext_vector_type(4)));

#define SLOPE 0.01f
#define EPB 64

__device__ __forceinline__ float leaky(float x) { return x >= 0.f ? x : SLOPE * x; }

__device__ __forceinline__ u16 f2b(float f) {          // round-to-nearest-even
    union { float f; unsigned u; } v; v.f = f;
    unsigned r = v.u + 0x7FFFu + ((v.u >> 16) & 1u);
    return (u16)(r >> 16);
}
__device__ __forceinline__ float b2f(u16 b) {
    union { unsigned u; float f; } v; v.u = ((unsigned)b) << 16; return v.f;
}

// ---------------------------------------------------------------------------
// Init: edge part (deg histogram + recvf mark + eact flag) and node (tflag).
// ---------------------------------------------------------------------------
__global__ __launch_bounds__(256) void k_init(
    const int* __restrict__ src, const int* __restrict__ dst,
    const int* __restrict__ ntype, int* __restrict__ deg,
    float* __restrict__ recvf, int* __restrict__ tflag,
    char* __restrict__ eact, int E, int N)
{
    int i = blockIdx.x * 256 + threadIdx.x;
    if (i < E) {
        bool p = (ntype[src[i]] == 2);
        eact[i] = p ? 1 : 0;
        if (p) {
            int d = dst[i];
            atomicAdd(&deg[d], 1);
            recvf[d] = 1.0f;
        }
    } else {
        int j = i - E;
        if (j < N) tflag[j] = (ntype[j] == 2) ? 1 : 0;
    }
}

// ---------------------------------------------------------------------------
// Dual scan step 1: per-256-chunk sums.  y=0: deg->bsum, y=1: tflag->bsum2.
// ---------------------------------------------------------------------------
__global__ __launch_bounds__(256) void k_scan1(
    const int* __restrict__ deg, const int* __restrict__ tflag,
    int* __restrict__ bsum, int* __restrict__ bsum2, int n)
{
    __shared__ int s[256];
    const int* v = blockIdx.y ? tflag : deg;
    int* out = blockIdx.y ? bsum2 : bsum;
    int i = blockIdx.x * 256 + threadIdx.x;
    s[threadIdx.x] = (i < n) ? v[i] : 0;
    __syncthreads();
    for (int o = 128; o > 0; o >>= 1) {
        if (threadIdx.x < o) s[threadIdx.x] += s[threadIdx.x + o];
        __syncthreads();
    }
    if (threadIdx.x == 0) out[blockIdx.x] = s[0];
}

// ---------------------------------------------------------------------------
// Dual scan step 2: exclusive scan of block sums (nb <= 256) + total.
// ---------------------------------------------------------------------------
__global__ __launch_bounds__(256) void k_scan2(
    int* __restrict__ bsum, int* __restrict__ bsum2, int nb,
    int* __restrict__ cntp, int* __restrict__ tcntp)
{
    __shared__ int s[256];
    int* arr = blockIdx.x ? bsum2 : bsum;
    int* tot = blockIdx.x ? tcntp : cntp;
    int v = (threadIdx.x < nb) ? arr[threadIdx.x] : 0;
    s[threadIdx.x] = v;
    __syncthreads();
    for (int o = 1; o < 256; o <<= 1) {
        int x = (threadIdx.x >= o) ? s[threadIdx.x - o] : 0;
        __syncthreads();
        s[threadIdx.x] += x;
        __syncthreads();
    }
    if (threadIdx.x < nb) arr[threadIdx.x] = s[threadIdx.x] - v;  // exclusive
    if (threadIdx.x == 255) *tot = s[255];                        // total
}

// ---------------------------------------------------------------------------
// Dual scan step 3: per-element exclusive offsets.
// y=0: deg -> cursor.  y=1: tflag -> trank, and tlist[trank[i]] = i.
// ---------------------------------------------------------------------------
__global__ __launch_bounds__(256) void k_scan3(
    const int* __restrict__ deg, const int* __restrict__ tflag,
    const int* __restrict__ bsum, const int* __restrict__ bsum2,
    int* __restrict__ cursor, int* __restrict__ trank,
    int* __restrict__ tlist, int n)
{
    __shared__ int s[256];
    const int sel = blockIdx.y;
    const int* v = sel ? tflag : deg;
    const int* bexcl = sel ? bsum2 : bsum;
    int i = blockIdx.x * 256 + threadIdx.x;
    int x = (i < n) ? v[i] : 0;
    s[threadIdx.x] = x;
    __syncthreads();
    for (int o = 1; o < 256; o <<= 1) {
        int y = (threadIdx.x >= o) ? s[threadIdx.x - o] : 0;
        __syncthreads();
        s[threadIdx.x] += y;
        __syncthreads();
    }
    if (i < n) {
        int off = bexcl[blockIdx.x] + s[threadIdx.x] - x;
        if (sel) {
            trank[i] = off;
            if (x) tlist[off] = i;
        } else {
            cursor[i] = off;
        }
    }
}

// ---------------------------------------------------------------------------
// Scatter active edges into dst-sorted order via per-dst cursors.
// Uses precomputed eact flag (coalesced) instead of re-gathering ntype.
// After this kernel, cursor[d] = END offset of d's segment.
// ---------------------------------------------------------------------------
__global__ __launch_bounds__(256) void k_scatter_pos(
    const int* __restrict__ src, const int* __restrict__ dst,
    const char* __restrict__ eact, const int* __restrict__ trank,
    int* __restrict__ cursor, int* __restrict__ eS,
    int* __restrict__ sSg, int E)
{
    int e = blockIdx.x * 256 + threadIdx.x;
    if (e < E && eact[e]) {
        int d = dst[e];
        int p = atomicAdd(&cursor[d], 1);
        eS[p] = e; sSg[p] = trank[src[e]];
    }
}

// ---------------------------------------------------------------------------
// Prep (merged): [0, n4)           nf -> bf16
//                [n4, n4+221184)   weight transposes (3 layers)
//                [.., .. + E*16)   efgather: one float4 chunk per thread
// ---------------------------------------------------------------------------
__global__ __launch_bounds__(256) void k_prep(
    const float* __restrict__ nf, u16* __restrict__ hb0, int n4,
    const float* __restrict__ We0, const float* __restrict__ We1,
    const float* __restrict__ We2, const float* __restrict__ Wn0,
    const float* __restrict__ Wn1, const float* __restrict__ Wn2,
    u16* __restrict__ WTe, u16* __restrict__ WTn, u16* __restrict__ WTef,
    const float* __restrict__ ef, const int* __restrict__ eS,
    const int* __restrict__ cntp, u16* __restrict__ efS, int E)
{
    int i = blockIdx.x * 256 + threadIdx.x;
    if (i < n4) {
        float4 v = ((const float4*)nf)[i];
        ushort4 o;
        o.x = f2b(v.x); o.y = f2b(v.y); o.z = f2b(v.z); o.w = f2b(v.w);
        ((ushort4*)hb0)[i] = o;
        return;
    }
    int j = i - n4;
    if (j < 3 * 73728) {
        int l = j / 73728;
        int idx = j - l * 73728;
        const float* We = (l == 0) ? We0 : (l == 1) ? We1 : We2;
        const float* Wn = (l == 0) ? Wn0 : (l == 1) ? Wn1 : Wn2;
        if (idx < 32768) {
            int sel = idx >> 14, jj = idx & 16383;
            int k = jj >> 7, n = jj & 127;
            WTe[(size_t)l * 32768 + sel * 16384 + n * 128 + k] = f2b(We[sel * 16384 + jj]);
        } else if (idx < 65536) {
            int jj = idx - 32768;
            int k = jj >> 7, n = jj & 127;
            WTn[(size_t)l * 32768 + n * 256 + k] = f2b(Wn[jj]);
        } else {
            int jj = idx - 65536;
            int k = jj >> 7, n = jj & 127;
            WTef[(size_t)l * 8192 + n * 64 + k] = f2b(We[32768 + jj]);
        }
        return;
    }
    int g = j - 3 * 73728;               // efgather chunk id
    if (g >= E * 16) return;
    int p = g >> 4, f4 = g & 15;
    if (p < *cntp) {
        float4 v = *(const float4*)(ef + (size_t)eS[p] * 64 + f4 * 4);
        ushort4 o;
        o.x = f2b(v.x); o.y = f2b(v.y); o.z = f2b(v.z); o.w = f2b(v.w);
        *(ushort4*)(efS + (size_t)p * 64 + f4 * 4) = o;
    }
}

// ---------------------------------------------------------------------------
// MERGED per-layer producer, 64-row GEMM tiles for better CU coverage.
// blocks [0, nT64)        = Tsrc-half GEMM over task ranks (most exit early)
//        [nT64, 2*nT64)   = Tdst-half GEMM over all N rows
//        [2*nT64, +gM)    = edge matvec msgS tiles
// Tile 64x128, 4 waves as 2x2 of 32x64, acc[2][4].
// ---------------------------------------------------------------------------
__global__ __launch_bounds__(256) void k_T2msg(
    const u16* __restrict__ A, const u16* __restrict__ WTe_l,
    u16* __restrict__ Tsrc, u16* __restrict__ Tdst,
    const int* __restrict__ tlist, const int* __restrict__ tcntp,
    const u16* __restrict__ efS, const u16* __restrict__ WTef_l,
    const int* __restrict__ cntp, u16* __restrict__ msgS,
    int Nfull, int nT64)
{
    __shared__ u16 sh[64 * 72 + 128 * 72];   // 27.6 KB union
    const int t = threadIdx.x;
    const int bx = blockIdx.x;
    const int w = t >> 6, lane = t & 63;
    const int lo = lane & 15, q = lane >> 4;

    if (bx < 2 * nT64) {
        // ---------------- GEMM half (64 x 128 tile, K=128) ----------------
        u16 (*As)[72] = (u16(*)[72])sh;
        u16 (*Bs)[72] = (u16(*)[72])(sh + 64 * 72);
        const int sel = (bx >= nT64) ? 1 : 0;
        const int M = sel ? Nfull : *tcntp;
        const int m0 = (bx - sel * nT64) * 64;
        if (m0 >= M) return;
        const u16* WT = WTe_l + sel * 16384;
        u16* T = sel ? Tdst : Tsrc;
        const int wm = w >> 1, wn = w & 1;
        f32x4 acc[2][4] = {};

        for (int kt = 0; kt < 128; kt += 64) {
            #pragma unroll
            for (int p = 0; p < 2; ++p) {        // A: 512 int4 chunks
                int c = t + p * 256;
                int row = c >> 3, k8 = c & 7;
                int gm = m0 + row;
                int4 va = make_int4(0, 0, 0, 0);
                if (gm < M) {
                    int arow = sel ? gm : tlist[gm];
                    va = *(const int4*)(A + (size_t)arow * 128 + kt + k8 * 8);
                }
                *(int4*)&As[row][k8 * 8] = va;
            }
            #pragma unroll
            for (int p = 0; p < 4; ++p) {        // B: 1024 int4 chunks
                int c = t + p * 256;
                int row = c >> 3, k8 = c & 7;
                *(int4*)&Bs[row][k8 * 8] =
                    *(const int4*)(WT + (size_t)row * 128 + kt + k8 * 8);
            }
            __syncthreads();
            #pragma unroll
            for (int kf = 0; kf < 2; ++kf) {
                s16x8 a[2], b[4];
                #pragma unroll
                for (int mi = 0; mi < 2; ++mi)
                    a[mi] = *(const s16x8*)&As[wm * 32 + mi * 16 + lo][kf * 32 + q * 8];
                #pragma unroll
                for (int ni = 0; ni < 4; ++ni)
                    b[ni] = *(const s16x8*)&Bs[wn * 64 + ni * 16 + lo][kf * 32 + q * 8];
                #pragma unroll
                for (int mi = 0; mi < 2; ++mi)
                    #pragma unroll
                    for (int ni = 0; ni < 4; ++ni)
                        acc[mi][ni] = __builtin_amdgcn_mfma_f32_16x16x32_bf16(
                            a[mi], b[ni], acc[mi][ni], 0, 0, 0);
            }
            __syncthreads();
        }
        #pragma unroll
        for (int mi = 0; mi < 2; ++mi) {
            #pragma unroll
            for (int r = 0; r < 4; ++r) {
                int gm = m0 + wm * 32 + mi * 16 + q * 4 + r;
                if (gm < M) {
                    #pragma unroll
                    for (int ni = 0; ni < 4; ++ni)
                        T[(size_t)gm * 128 + wn * 64 + ni * 16 + lo] = f2b(acc[mi][ni][r]);
                }
            }
        }
    } else {
        // ---------------- edge matvec tile ----------------
        u16 (*Ms)[136] = (u16(*)[136])sh;
        const int cnt = *cntp;
        const int b0 = (bx - 2 * nT64) * EPB;
        if (b0 >= cnt) return;
        const int ei = w * 16 + lo;
        const int p = b0 + ei;

        f32x4 acc[8] = {};
        #pragma unroll
        for (int kf = 0; kf < 2; ++kf) {
            s16x8 b = {};
            if (p < cnt) b = *(const s16x8*)(efS + (size_t)p * 64 + kf * 32 + q * 8);
            #pragma unroll
            for (int mi = 0; mi < 8; ++mi) {
                s16x8 a = *(const s16x8*)(WTef_l + (size_t)(mi * 16 + lo) * 64 + kf * 32 + q * 8);
                acc[mi] = __builtin_amdgcn_mfma_f32_16x16x32_bf16(a, b, acc[mi], 0, 0, 0);
            }
        }
        // D mapping: col=lane&15 (edge), row = mi*16 + q*4 + r (feature n)
        #pragma unroll
        for (int mi = 0; mi < 8; ++mi) {
            ushort4 o;
            o.x = f2b(acc[mi][0]); o.y = f2b(acc[mi][1]);
            o.z = f2b(acc[mi][2]); o.w = f2b(acc[mi][3]);
            *(ushort4*)&Ms[ei][mi * 16 + q * 4] = o;
        }
        __syncthreads();
        #pragma unroll
        for (int pz = 0; pz < 4; ++pz) {
            int idx = t + pz * 256;
            int rrow = idx >> 4, c8 = idx & 15;
            int pp = b0 + rrow;
            if (pp < cnt)
                *(int4*)(msgS + (size_t)pp * 128 + c8 * 8) = *(const int4*)&Ms[rrow][c8 * 8];
        }
    }
}

// ---------------------------------------------------------------------------
// CSR segmented reduce: one wave per dst node, NO atomics, plain bf16 store.
// ---------------------------------------------------------------------------
__global__ __launch_bounds__(256) void k_reduce(
    const u16* __restrict__ msgS, const u16* __restrict__ Tsrc,
    const u16* __restrict__ Tdst, const int* __restrict__ sSg,
    const int* __restrict__ deg, const int* __restrict__ segEnd,
    u16* __restrict__ redb, int N)
{
    const int w = threadIdx.x >> 6, lane = threadIdx.x & 63;
    const int d = blockIdx.x * 4 + w;
    if (d >= N) return;
    const int dg = deg[d];
    if (dg == 0) return;                 // recv=0 masks these rows downstream
    const int end = segEnd[d], beg = end - dg;

    unsigned td = *(const unsigned*)(Tdst + (size_t)d * 128 + lane * 2);
    const float td0 = b2f((u16)(td & 0xffff)), td1 = b2f((u16)(td >> 16));
    float a0 = 0.f, a1 = 0.f;
    for (int i = beg; i < end; ++i) {
        int s = sSg[i];                  // uniform across wave -> broadcast
        unsigned m  = *(const unsigned*)(msgS + (size_t)i * 128 + lane * 2);
        unsigned ts = *(const unsigned*)(Tsrc + (size_t)s * 128 + lane * 2);
        a0 += leaky(b2f((u16)(m & 0xffff)) + b2f((u16)(ts & 0xffff)) + td0);
        a1 += leaky(b2f((u16)(m >> 16))    + b2f((u16)(ts >> 16))    + td1);
    }
    unsigned out = (unsigned)f2b(a0) | ((unsigned)f2b(a1) << 16);
    *(unsigned*)(redb + (size_t)d * 128 + lane * 2) = out;
}

// ---------------------------------------------------------------------------
// out = leaky([H | R] @ Wn) * recv.  64x128 tile, K=256.
// ---------------------------------------------------------------------------
__global__ __launch_bounds__(256) void k_gemm_node(
    const u16* __restrict__ H, const u16* __restrict__ R,
    const u16* __restrict__ WT, const float* __restrict__ recvf,
    u16* __restrict__ O16, float* __restrict__ O32, int fin, int M)
{
    __shared__ u16 As[64][72];
    __shared__ u16 Bs[128][72];
    const int t = threadIdx.x;
    const int m0 = blockIdx.x * 64;
    if (m0 >= M) return;
    const int w = t >> 6, lane = t & 63;
    const int lo = lane & 15, q = lane >> 4;
    const int wm = w >> 1, wn = w & 1;
    f32x4 acc[2][4] = {};

    for (int kt = 0; kt < 256; kt += 64) {
        const u16* Ap = (kt < 128) ? (H + kt) : (R + (kt - 128));
        #pragma unroll
        for (int p = 0; p < 2; ++p) {            // A: 512 int4 chunks
            int c = t + p * 256;
            int row = c >> 3, k8 = c & 7;
            int gm = m0 + row;
            int4 va = make_int4(0, 0, 0, 0);
            if (gm < M) va = *(const int4*)(Ap + (size_t)gm * 128 + k8 * 8);
            *(int4*)&As[row][k8 * 8] = va;
        }
        #pragma unroll
        for (int p = 0; p < 4; ++p) {            // B: 1024 int4 chunks
            int c = t + p * 256;
            int row = c >> 3, k8 = c & 7;
            *(int4*)&Bs[row][k8 * 8] =
                *(const int4*)(WT + (size_t)row * 256 + kt + k8 * 8);
        }
        __syncthreads();
        #pragma unroll
        for (int kf = 0; kf < 2; ++kf) {
            s16x8 a[2], b[4];
            #pragma unroll
            for (int mi = 0; mi < 2; ++mi)
                a[mi] = *(const s16x8*)&As[wm * 32 + mi * 16 + lo][kf * 32 + q * 8];
            #pragma unroll
            for (int ni = 0; ni < 4; ++ni)
                b[ni] = *(const s16x8*)&Bs[wn * 64 + ni * 16 + lo][kf * 32 + q * 8];
            #pragma unroll
            for (int mi = 0; mi < 2; ++mi)
                #pragma unroll
                for (int ni = 0; ni < 4; ++ni)
                    acc[mi][ni] = __builtin_amdgcn_mfma_f32_16x16x32_bf16(
                        a[mi], b[ni], acc[mi][ni], 0, 0, 0);
        }
        __syncthreads();
    }
    #pragma unroll
    for (int mi = 0; mi < 2; ++mi) {
        #pragma unroll
        for (int r = 0; r < 4; ++r) {
            int gm = m0 + wm * 32 + mi * 16 + q * 4 + r;
            if (gm < M) {
                float rv = recvf[gm];
                #pragma unroll
                for (int ni = 0; ni < 4; ++ni) {
                    float val = leaky(acc[mi][ni][r]) * rv;
                    size_t o = (size_t)gm * 128 + wn * 64 + ni * 16 + lo;
                    if (fin) O32[o] = val;
                    else     O16[o] = f2b(val);
                }
            }
        }
    }
}

// ---------------------------------------------------------------------------
extern "C" void kernel_launch(void* const* d_in, const int* in_sizes, int n_in,
                              void* d_out, int out_size, void* d_ws, size_t ws_size,
                              hipStream_t stream)
{
    const float* nf    = (const float*)d_in[0];
    const float* ef    = (const float*)d_in[1];
    const int*   src   = (const int*)d_in[2];
    const int*   dst   = (const int*)d_in[3];
    const int*   ntype = (const int*)d_in[4];
    const float* We[3] = {(const float*)d_in[5], (const float*)d_in[7], (const float*)d_in[9]};
    const float* Wn[3] = {(const float*)d_in[6], (const float*)d_in[8], (const float*)d_in[10]};

    const int N = in_sizes[0] / 128;
    const int E = in_sizes[1] / 64;

    u16* Tsrc = (u16*)d_ws;                        // N*128 (only *tcnt used)
    u16* Tdst = Tsrc + (size_t)N * 128;            // N*128
    u16* hb0  = Tdst + (size_t)N * 128;            // N*128
    u16* hb1  = hb0 + (size_t)N * 128;             // N*128
    u16* redb = hb1 + (size_t)N * 128;             // N*128 bf16
    u16* WTe  = redb + (size_t)N * 128;            // 3*32768
    u16* WTn  = WTe + 3 * 32768;                   // 3*32768
    u16* WTef = WTn + 3 * 32768;                   // 3*8192
    u16* efS  = WTef + 3 * 8192;                   // E*64 (only cnt*64 used)
    u16* msgS = efS + (size_t)E * 64;              // E*128 (only cnt*128 used)
    float* recvf = (float*)(msgS + (size_t)E * 128); // N  } zeroed together
    int* deg    = (int*)(recvf + N);               // N    }
    int* cursor = deg + N;                         // N (becomes segment END)
    int* tflag  = cursor + N;                      // N
    int* trank  = tflag + N;                       // N
    int* tlist  = trank + N;                       // N
    int* bsum   = tlist + N;                       // 256
    int* bsum2  = bsum + 256;                      // 256
    int* cntp   = bsum2 + 256;                     // 1 (+pad)
    int* tcntp  = cntp + 4;                        // 1 (+pad)
    int* eS     = tcntp + 4;                       // E
    int* sSg    = eS + E;                          // E
    char* eact  = (char*)(sSg + E);                // E bytes

    const int nb  = (N + 255) / 256;               // 196 <= 256 ok
    const int gEb = (E + 255) / 256;
    const int n4  = N * 128 / 4;
    const int nT64 = (N + 63) / 64;
    const int gM  = (E + EPB - 1) / EPB;
    const int prepWork = n4 + 3 * 73728 + E * 16;

    hipMemsetAsync(recvf, 0, (size_t)N * 2 * sizeof(float), stream);

    k_init<<<(E + N + 255) / 256, 256, 0, stream>>>(src, dst, ntype, deg, recvf, tflag, eact, E, N);
    k_scan1<<<dim3(nb, 2), 256, 0, stream>>>(deg, tflag, bsum, bsum2, N);
    k_scan2<<<2, 256, 0, stream>>>(bsum, bsum2, nb, cntp, tcntp);
    k_scan3<<<dim3(nb, 2), 256, 0, stream>>>(deg, tflag, bsum, bsum2, cursor, trank, tlist, N);
    k_scatter_pos<<<gEb, 256, 0, stream>>>(src, dst, eact, trank, cursor, eS, sSg, E);
    k_prep<<<(prepWork + 255) / 256, 256, 0, stream>>>(
        nf, hb0, n4, We[0], We[1], We[2], Wn[0], Wn[1], Wn[2], WTe, WTn, WTef,
        ef, eS, cntp, efS, E);

    int gR = (N + 3) / 4;

    const u16* hIn[3]  = {hb0, hb1, hb0};
    u16*       hOut[3] = {hb1, hb0, hb1};
    for (int l = 0; l < 3; ++l) {
        int fin = (l == 2);
        k_T2msg<<<2 * nT64 + gM, 256, 0, stream>>>(
            hIn[l], WTe + (size_t)l * 32768, Tsrc, Tdst, tlist, tcntp,
            efS, WTef + (size_t)l * 8192, cntp, msgS, N, nT64);
        k_reduce<<<gR, 256, 0, stream>>>(msgS, Tsrc, Tdst, sSg, deg, cursor, redb, N);
        k_gemm_node<<<nT64, 256, 0, stream>>>(hIn[l], redb, WTn + (size_t)l * 32768,
                                              recvf, hOut[l], (float*)d_out, fin, N);
    }
}

// Round 15
// 299.030 us; speedup vs baseline: 1.6822x; 1.0565x over previous
//
#include <hip/hip_runtime.h>

typedef unsigned short u16;
typedef short s16x8 __attribute__((ext_vector_type(8)));
typedef float f32x4 __attribute__((ext_vector_type(4)));

#define SLOPE 0.01f
#define EPB 64
#define MSGB 2048

__device__ __forceinline__ float leaky(float x) { return x >= 0.f ? x : SLOPE * x; }

__device__ __forceinline__ u16 f2b(float f) {          // round-to-nearest-even
    union { float f; unsigned u; } v; v.f = f;
    unsigned r = v.u + 0x7FFFu + ((v.u >> 16) & 1u);
    return (u16)(r >> 16);
}
__device__ __forceinline__ float b2f(u16 b) {
    union { unsigned u; float f; } v; v.u = ((unsigned)b) << 16; return v.f;
}

// ---------------------------------------------------------------------------
// Init (merged): [0,E) edge part (eact + deg histogram); [E,E+N) tflag;
// [E+N, E+N+n4) nf->bf16; tail: weight transposes (3 layers).
// ---------------------------------------------------------------------------
__global__ __launch_bounds__(256) void k_init(
    const int* __restrict__ src, const int* __restrict__ dst,
    const int* __restrict__ ntype, int* __restrict__ deg,
    int* __restrict__ tflag, char* __restrict__ eact,
    const float* __restrict__ nf, u16* __restrict__ hb0, int n4,
    const float* __restrict__ We0, const float* __restrict__ We1,
    const float* __restrict__ We2, const float* __restrict__ Wn0,
    const float* __restrict__ Wn1, const float* __restrict__ Wn2,
    u16* __restrict__ WTe, u16* __restrict__ WTn, u16* __restrict__ WTef,
    int E, int N)
{
    int i = blockIdx.x * 256 + threadIdx.x;
    if (i < E) {
        bool p = (ntype[src[i]] == 2);
        eact[i] = p ? 1 : 0;
        if (p) atomicAdd(&deg[dst[i]], 1);
        return;
    }
    i -= E;
    if (i < N) { tflag[i] = (ntype[i] == 2) ? 1 : 0; return; }
    i -= N;
    if (i < n4) {
        float4 v = ((const float4*)nf)[i];
        ushort4 o;
        o.x = f2b(v.x); o.y = f2b(v.y); o.z = f2b(v.z); o.w = f2b(v.w);
        ((ushort4*)hb0)[i] = o;
        return;
    }
    int j = i - n4;
    if (j >= 3 * 73728) return;
    int l = j / 73728;
    int idx = j - l * 73728;
    const float* We = (l == 0) ? We0 : (l == 1) ? We1 : We2;
    const float* Wn = (l == 0) ? Wn0 : (l == 1) ? Wn1 : Wn2;
    if (idx < 32768) {
        int sel = idx >> 14, jj = idx & 16383;
        int k = jj >> 7, n = jj & 127;
        WTe[(size_t)l * 32768 + sel * 16384 + n * 128 + k] = f2b(We[sel * 16384 + jj]);
    } else if (idx < 65536) {
        int jj = idx - 32768;
        int k = jj >> 7, n = jj & 127;
        WTn[(size_t)l * 32768 + n * 256 + k] = f2b(Wn[jj]);
    } else {
        int jj = idx - 65536;
        int k = jj >> 7, n = jj & 127;
        WTef[(size_t)l * 8192 + n * 64 + k] = f2b(We[32768 + jj]);
    }
}

// ---------------------------------------------------------------------------
// Scan step 1: per-256-chunk sums.  y=0: deg->bsum AND recvf=(deg>0);
// y=1: tflag->bsum2.
// ---------------------------------------------------------------------------
__global__ __launch_bounds__(256) void k_scan1(
    const int* __restrict__ deg, const int* __restrict__ tflag,
    int* __restrict__ bsum, int* __restrict__ bsum2,
    float* __restrict__ recvf, int n)
{
    __shared__ int s[256];
    const int sel = blockIdx.y;
    const int* v = sel ? tflag : deg;
    int* out = sel ? bsum2 : bsum;
    int i = blockIdx.x * 256 + threadIdx.x;
    int x = (i < n) ? v[i] : 0;
    if (!sel && i < n) recvf[i] = (x > 0) ? 1.0f : 0.0f;
    s[threadIdx.x] = x;
    __syncthreads();
    for (int o = 128; o > 0; o >>= 1) {
        if (threadIdx.x < o) s[threadIdx.x] += s[threadIdx.x + o];
        __syncthreads();
    }
    if (threadIdx.x == 0) out[blockIdx.x] = s[0];
}

// ---------------------------------------------------------------------------
// Scan steps 2+3 merged: every block locally scans the nb (<=256) block sums,
// then computes per-element exclusive offsets.
// y=0: deg -> cursor, total -> cntp.  y=1: tflag -> trank/tlist, -> tcntp.
// ---------------------------------------------------------------------------
__global__ __launch_bounds__(256) void k_scan23(
    const int* __restrict__ deg, const int* __restrict__ tflag,
    const int* __restrict__ bsum, const int* __restrict__ bsum2,
    int* __restrict__ cursor, int* __restrict__ trank,
    int* __restrict__ tlist, int* __restrict__ cntp, int* __restrict__ tcntp,
    int n, int nb)
{
    __shared__ int bscan[256];
    __shared__ int s[256];
    const int sel = blockIdx.y;
    const int* v = sel ? tflag : deg;
    const int* bs = sel ? bsum2 : bsum;
    const int t = threadIdx.x;

    int bv = (t < nb) ? bs[t] : 0;
    bscan[t] = bv;
    __syncthreads();
    for (int o = 1; o < 256; o <<= 1) {
        int x = (t >= o) ? bscan[t - o] : 0;
        __syncthreads();
        bscan[t] += x;
        __syncthreads();
    }
    const int base  = (blockIdx.x > 0) ? bscan[blockIdx.x - 1] : 0;
    const int total = bscan[nb - 1];

    int i = blockIdx.x * 256 + t;
    int x = (i < n) ? v[i] : 0;
    s[t] = x;
    __syncthreads();
    for (int o = 1; o < 256; o <<= 1) {
        int y = (t >= o) ? s[t - o] : 0;
        __syncthreads();
        s[t] += y;
        __syncthreads();
    }
    if (i < n) {
        int off = base + s[t] - x;
        if (sel) {
            trank[i] = off;
            if (x) tlist[off] = i;
        } else {
            cursor[i] = off;
        }
    }
    if (blockIdx.x == 0 && t == 0) *(sel ? tcntp : cntp) = total;
}

// ---------------------------------------------------------------------------
// Scatter active edges into dst-sorted order via per-dst cursors.
// Packed write: esPair[p] = {edge id, src task-rank}.
// After this kernel, cursor[d] = END offset of d's segment.
// ---------------------------------------------------------------------------
__global__ __launch_bounds__(256) void k_scatter_pos(
    const int* __restrict__ src, const int* __restrict__ dst,
    const char* __restrict__ eact, const int* __restrict__ trank,
    int* __restrict__ cursor, int2* __restrict__ esPair, int E)
{
    int e = blockIdx.x * 256 + threadIdx.x;
    if (e < E && eact[e]) {
        int d = dst[e];
        int p = atomicAdd(&cursor[d], 1);
        esPair[p] = make_int2(e, trank[src[e]]);
    }
}

// ---------------------------------------------------------------------------
// efgather: fixed grid, grid-stride over cnt*16 float4 chunks.
// ---------------------------------------------------------------------------
__global__ __launch_bounds__(256) void k_efg(
    const float* __restrict__ ef, const int2* __restrict__ esPair,
    const int* __restrict__ cntp, u16* __restrict__ efS)
{
    const int chunks = (*cntp) * 16;
    const int stride = gridDim.x * 256;
    for (int c = blockIdx.x * 256 + threadIdx.x; c < chunks; c += stride) {
        int p = c >> 4, f4 = c & 15;
        float4 v = *(const float4*)(ef + (size_t)esPair[p].x * 64 + f4 * 4);
        ushort4 o;
        o.x = f2b(v.x); o.y = f2b(v.y); o.z = f2b(v.z); o.w = f2b(v.w);
        *(ushort4*)(efS + (size_t)p * 64 + f4 * 4) = o;
    }
}

// ---------------------------------------------------------------------------
// MERGED per-layer producer: blocks [0, nT64) = Tsrc-half GEMM (task ranks),
// [nT64, 2*nT64) = Tdst-half GEMM, [2*nT64, 2*nT64+MSGB) = msg tiles
// (grid-stride over cnt/64 tiles — no dead blocks).
// ---------------------------------------------------------------------------
__global__ __launch_bounds__(256) void k_T2msg(
    const u16* __restrict__ A, const u16* __restrict__ WTe_l,
    u16* __restrict__ Tsrc, u16* __restrict__ Tdst,
    const int* __restrict__ tlist, const int* __restrict__ tcntp,
    const u16* __restrict__ efS, const u16* __restrict__ WTef_l,
    const int* __restrict__ cntp, u16* __restrict__ msgS,
    int Nfull, int nT64)
{
    __shared__ u16 sh[64 * 72 + 128 * 72];   // 27.6 KB union
    const int t = threadIdx.x;
    const int bx = blockIdx.x;
    const int w = t >> 6, lane = t & 63;
    const int lo = lane & 15, q = lane >> 4;

    if (bx < 2 * nT64) {
        // ---------------- GEMM half (64 x 128 tile, K=128) ----------------
        u16 (*As)[72] = (u16(*)[72])sh;
        u16 (*Bs)[72] = (u16(*)[72])(sh + 64 * 72);
        const int sel = (bx >= nT64) ? 1 : 0;
        const int M = sel ? Nfull : *tcntp;
        const int m0 = (bx - sel * nT64) * 64;
        if (m0 >= M) return;
        const u16* WT = WTe_l + sel * 16384;
        u16* T = sel ? Tdst : Tsrc;
        const int wm = w >> 1, wn = w & 1;
        f32x4 acc[2][4] = {};

        for (int kt = 0; kt < 128; kt += 64) {
            #pragma unroll
            for (int p = 0; p < 2; ++p) {        // A: 512 int4 chunks
                int c = t + p * 256;
                int row = c >> 3, k8 = c & 7;
                int gm = m0 + row;
                int4 va = make_int4(0, 0, 0, 0);
                if (gm < M) {
                    int arow = sel ? gm : tlist[gm];
                    va = *(const int4*)(A + (size_t)arow * 128 + kt + k8 * 8);
                }
                *(int4*)&As[row][k8 * 8] = va;
            }
            #pragma unroll
            for (int p = 0; p < 4; ++p) {        // B: 1024 int4 chunks
                int c = t + p * 256;
                int row = c >> 3, k8 = c & 7;
                *(int4*)&Bs[row][k8 * 8] =
                    *(const int4*)(WT + (size_t)row * 128 + kt + k8 * 8);
            }
            __syncthreads();
            #pragma unroll
            for (int kf = 0; kf < 2; ++kf) {
                s16x8 a[2], b[4];
                #pragma unroll
                for (int mi = 0; mi < 2; ++mi)
                    a[mi] = *(const s16x8*)&As[wm * 32 + mi * 16 + lo][kf * 32 + q * 8];
                #pragma unroll
                for (int ni = 0; ni < 4; ++ni)
                    b[ni] = *(const s16x8*)&Bs[wn * 64 + ni * 16 + lo][kf * 32 + q * 8];
                #pragma unroll
                for (int mi = 0; mi < 2; ++mi)
                    #pragma unroll
                    for (int ni = 0; ni < 4; ++ni)
                        acc[mi][ni] = __builtin_amdgcn_mfma_f32_16x16x32_bf16(
                            a[mi], b[ni], acc[mi][ni], 0, 0, 0);
            }
            __syncthreads();
        }
        #pragma unroll
        for (int mi = 0; mi < 2; ++mi) {
            #pragma unroll
            for (int r = 0; r < 4; ++r) {
                int gm = m0 + wm * 32 + mi * 16 + q * 4 + r;
                if (gm < M) {
                    #pragma unroll
                    for (int ni = 0; ni < 4; ++ni)
                        T[(size_t)gm * 128 + wn * 64 + ni * 16 + lo] = f2b(acc[mi][ni][r]);
                }
            }
        }
    } else {
        // ---------------- edge matvec tiles (grid-stride) ----------------
        u16 (*Ms)[136] = (u16(*)[136])sh;
        const int cnt = *cntp;
        const int ei = w * 16 + lo;
        for (int tile = bx - 2 * nT64; tile * EPB < cnt; tile += MSGB) {
            const int b0 = tile * EPB;
            const int p = b0 + ei;

            f32x4 acc[8] = {};
            #pragma unroll
            for (int kf = 0; kf < 2; ++kf) {
                s16x8 b = {};
                if (p < cnt) b = *(const s16x8*)(efS + (size_t)p * 64 + kf * 32 + q * 8);
                #pragma unroll
                for (int mi = 0; mi < 8; ++mi) {
                    s16x8 a = *(const s16x8*)(WTef_l + (size_t)(mi * 16 + lo) * 64 + kf * 32 + q * 8);
                    acc[mi] = __builtin_amdgcn_mfma_f32_16x16x32_bf16(a, b, acc[mi], 0, 0, 0);
                }
            }
            // D mapping: col=lane&15 (edge), row = mi*16 + q*4 + r (feature n)
            #pragma unroll
            for (int mi = 0; mi < 8; ++mi) {
                ushort4 o;
                o.x = f2b(acc[mi][0]); o.y = f2b(acc[mi][1]);
                o.z = f2b(acc[mi][2]); o.w = f2b(acc[mi][3]);
                *(ushort4*)&Ms[ei][mi * 16 + q * 4] = o;
            }
            __syncthreads();
            #pragma unroll
            for (int pz = 0; pz < 4; ++pz) {
                int idx = t + pz * 256;
                int rrow = idx >> 4, c8 = idx & 15;
                int pp = b0 + rrow;
                if (pp < cnt)
                    *(int4*)(msgS + (size_t)pp * 128 + c8 * 8) = *(const int4*)&Ms[rrow][c8 * 8];
            }
            __syncthreads();                     // Ms reuse guard
        }
    }
}

// ---------------------------------------------------------------------------
// CSR segmented reduce: one wave per dst node, NO atomics, plain bf16 store.
// ---------------------------------------------------------------------------
__global__ __launch_bounds__(256) void k_reduce(
    const u16* __restrict__ msgS, const u16* __restrict__ Tsrc,
    const u16* __restrict__ Tdst, const int2* __restrict__ esPair,
    const int* __restrict__ deg, const int* __restrict__ segEnd,
    u16* __restrict__ redb, int N)
{
    const int w = threadIdx.x >> 6, lane = threadIdx.x & 63;
    const int d = blockIdx.x * 4 + w;
    if (d >= N) return;
    const int dg = deg[d];
    if (dg == 0) return;                 // recv=0 masks these rows downstream
    const int end = segEnd[d], beg = end - dg;

    unsigned td = *(const unsigned*)(Tdst + (size_t)d * 128 + lane * 2);
    const float td0 = b2f((u16)(td & 0xffff)), td1 = b2f((u16)(td >> 16));
    float a0 = 0.f, a1 = 0.f;
    for (int i = beg; i < end; ++i) {
        int s = esPair[i].y;             // uniform across wave -> broadcast
        unsigned m  = *(const unsigned*)(msgS + (size_t)i * 128 + lane * 2);
        unsigned ts = *(const unsigned*)(Tsrc + (size_t)s * 128 + lane * 2);
        a0 += leaky(b2f((u16)(m & 0xffff)) + b2f((u16)(ts & 0xffff)) + td0);
        a1 += leaky(b2f((u16)(m >> 16))    + b2f((u16)(ts >> 16))    + td1);
    }
    unsigned out = (unsigned)f2b(a0) | ((unsigned)f2b(a1) << 16);
    *(unsigned*)(redb + (size_t)d * 128 + lane * 2) = out;
}

// ---------------------------------------------------------------------------
// out = leaky([H | R] @ Wn) * recv.  64x128 tile, K=256.
// ---------------------------------------------------------------------------
__global__ __launch_bounds__(256) void k_gemm_node(
    const u16* __restrict__ H, const u16* __restrict__ R,
    const u16* __restrict__ WT, const float* __restrict__ recvf,
    u16* __restrict__ O16, float* __restrict__ O32, int fin, int M)
{
    __shared__ u16 As[64][72];
    __shared__ u16 Bs[128][72];
    const int t = threadIdx.x;
    const int m0 = blockIdx.x * 64;
    if (m0 >= M) return;
    const int w = t >> 6, lane = t & 63;
    const int lo = lane & 15, q = lane >> 4;
    const int wm = w >> 1, wn = w & 1;
    f32x4 acc[2][4] = {};

    for (int kt = 0; kt < 256; kt += 64) {
        const u16* Ap = (kt < 128) ? (H + kt) : (R + (kt - 128));
        #pragma unroll
        for (int p = 0; p < 2; ++p) {            // A: 512 int4 chunks
            int c = t + p * 256;
            int row = c >> 3, k8 = c & 7;
            int gm = m0 + row;
            int4 va = make_int4(0, 0, 0, 0);
            if (gm < M) va = *(const int4*)(Ap + (size_t)gm * 128 + k8 * 8);
            *(int4*)&As[row][k8 * 8] = va;
        }
        #pragma unroll
        for (int p = 0; p < 4; ++p) {            // B: 1024 int4 chunks
            int c = t + p * 256;
            int row = c >> 3, k8 = c & 7;
            *(int4*)&Bs[row][k8 * 8] =
                *(const int4*)(WT + (size_t)row * 256 + kt + k8 * 8);
        }
        __syncthreads();
        #pragma unroll
        for (int kf = 0; kf < 2; ++kf) {
            s16x8 a[2], b[4];
            #pragma unroll
            for (int mi = 0; mi < 2; ++mi)
                a[mi] = *(const s16x8*)&As[wm * 32 + mi * 16 + lo][kf * 32 + q * 8];
            #pragma unroll
            for (int ni = 0; ni < 4; ++ni)
                b[ni] = *(const s16x8*)&Bs[wn * 64 + ni * 16 + lo][kf * 32 + q * 8];
            #pragma unroll
            for (int mi = 0; mi < 2; ++mi)
                #pragma unroll
                for (int ni = 0; ni < 4; ++ni)
                    acc[mi][ni] = __builtin_amdgcn_mfma_f32_16x16x32_bf16(
                        a[mi], b[ni], acc[mi][ni], 0, 0, 0);
        }
        __syncthreads();
    }
    #pragma unroll
    for (int mi = 0; mi < 2; ++mi) {
        #pragma unroll
        for (int r = 0; r < 4; ++r) {
            int gm = m0 + wm * 32 + mi * 16 + q * 4 + r;
            if (gm < M) {
                float rv = recvf[gm];
                #pragma unroll
                for (int ni = 0; ni < 4; ++ni) {
                    float val = leaky(acc[mi][ni][r]) * rv;
                    size_t o = (size_t)gm * 128 + wn * 64 + ni * 16 + lo;
                    if (fin) O32[o] = val;
                    else     O16[o] = f2b(val);
                }
            }
        }
    }
}

// ---------------------------------------------------------------------------
extern "C" void kernel_launch(void* const* d_in, const int* in_sizes, int n_in,
                              void* d_out, int out_size, void* d_ws, size_t ws_size,
                              hipStream_t stream)
{
    const float* nf    = (const float*)d_in[0];
    const float* ef    = (const float*)d_in[1];
    const int*   src   = (const int*)d_in[2];
    const int*   dst   = (const int*)d_in[3];
    const int*   ntype = (const int*)d_in[4];
    const float* We[3] = {(const float*)d_in[5], (const float*)d_in[7], (const float*)d_in[9]};
    const float* Wn[3] = {(const float*)d_in[6], (const float*)d_in[8], (const float*)d_in[10]};

    const int N = in_sizes[0] / 128;
    const int E = in_sizes[1] / 64;

    u16* Tsrc = (u16*)d_ws;                        // N*128 (only *tcnt used)
    u16* Tdst = Tsrc + (size_t)N * 128;            // N*128
    u16* hb0  = Tdst + (size_t)N * 128;            // N*128
    u16* hb1  = hb0 + (size_t)N * 128;             // N*128
    u16* redb = hb1 + (size_t)N * 128;             // N*128 bf16
    u16* WTe  = redb + (size_t)N * 128;            // 3*32768
    u16* WTn  = WTe + 3 * 32768;                   // 3*32768
    u16* WTef = WTn + 3 * 32768;                   // 3*8192
    u16* efS  = WTef + 3 * 8192;                   // E*64 (only cnt*64 used)
    u16* msgS = efS + (size_t)E * 64;              // E*128 (only cnt*128 used)
    float* recvf = (float*)(msgS + (size_t)E * 128); // N
    int* deg    = (int*)(recvf + N);               // N (memset)
    int* cursor = deg + N;                         // N (becomes segment END)
    int* tflag  = cursor + N;                      // N
    int* trank  = tflag + N;                       // N
    int* tlist  = trank + N;                       // N
    int* bsum   = tlist + N;                       // 256
    int* bsum2  = bsum + 256;                      // 256
    int* cntp   = bsum2 + 256;                     // 1 (+pad)
    int* tcntp  = cntp + 4;                        // 1 (+pad)
    int2* esPair = (int2*)(tcntp + 4);             // E int2
    char* eact  = (char*)(esPair + E);             // E bytes

    const int nb  = (N + 255) / 256;               // 196 <= 256 ok
    const int gEb = (E + 255) / 256;
    const int n4  = N * 128 / 4;
    const int nT64 = (N + 63) / 64;
    const int initWork = E + N + n4 + 3 * 73728;

    hipMemsetAsync(deg, 0, (size_t)N * sizeof(int), stream);
    k_init<<<(initWork + 255) / 256, 256, 0, stream>>>(
        src, dst, ntype, deg, tflag, eact, nf, hb0, n4,
        We[0], We[1], We[2], Wn[0], Wn[1], Wn[2], WTe, WTn, WTef, E, N);
    k_scan1<<<dim3(nb, 2), 256, 0, stream>>>(deg, tflag, bsum, bsum2, recvf, N);
    k_scan23<<<dim3(nb, 2), 256, 0, stream>>>(deg, tflag, bsum, bsum2,
                                              cursor, trank, tlist, cntp, tcntp, N, nb);
    k_scatter_pos<<<gEb, 256, 0, stream>>>(src, dst, eact, trank, cursor, esPair, E);
    k_efg<<<1024, 256, 0, stream>>>(ef, esPair, cntp, efS);

    int gR = (N + 3) / 4;

    const u16* hIn[3]  = {hb0, hb1, hb0};
    u16*       hOut[3] = {hb1, hb0, hb1};
    for (int l = 0; l < 3; ++l) {
        int fin = (l == 2);
        k_T2msg<<<2 * nT64 + MSGB, 256, 0, stream>>>(
            hIn[l], WTe + (size_t)l * 32768, Tsrc, Tdst, tlist, tcntp,
            efS, WTef + (size_t)l * 8192, cntp, msgS, N, nT64);
        k_reduce<<<gR, 256, 0, stream>>>(msgS, Tsrc, Tdst, esPair, deg, cursor, redb, N);
        k_gemm_node<<<nT64, 256, 0, stream>>>(hIn[l], redb, WTn + (size_t)l * 32768,
                                              recvf, hOut[l], (float*)d_out, fin, N);
    }
}

// Round 16
// 294.104 us; speedup vs baseline: 1.7104x; 1.0167x over previous
//
#include <hip/hip_runtime.h>

typedef unsigned short u16;
typedef short s16x8 __attribute__((ext_vector_type(8)));
typedef float f32x4 __attribute__((ext_vector_type(4)));

#define SLOPE 0.01f
#define EPB 64
#define MSGB 2048

__device__ __forceinline__ float leaky(float x) { return x >= 0.f ? x : SLOPE * x; }

__device__ __forceinline__ u16 f2b(float f) {          // round-to-nearest-even
    union { float f; unsigned u; } v; v.f = f;
    unsigned r = v.u + 0x7FFFu + ((v.u >> 16) & 1u);
    return (u16)(r >> 16);
}
__device__ __forceinline__ float b2f(u16 b) {
    union { unsigned u; float f; } v; v.u = ((unsigned)b) << 16; return v.f;
}

// ---------------------------------------------------------------------------
// Init (merged): [0,E) edge part (rank = within-dst order from deg histogram);
// [E,E+N) tflag; [E+N, +n4) nf->bf16; tail: weight transposes (3 layers).
// ---------------------------------------------------------------------------
__global__ __launch_bounds__(256) void k_init(
    const int* __restrict__ src, const int* __restrict__ dst,
    const int* __restrict__ ntype, int* __restrict__ deg,
    int* __restrict__ tflag, int* __restrict__ rank,
    const float* __restrict__ nf, u16* __restrict__ hb0, int n4,
    const float* __restrict__ We0, const float* __restrict__ We1,
    const float* __restrict__ We2, const float* __restrict__ Wn0,
    const float* __restrict__ Wn1, const float* __restrict__ Wn2,
    u16* __restrict__ WTe, u16* __restrict__ WTn, u16* __restrict__ WTef,
    int E, int N)
{
    int i = blockIdx.x * 256 + threadIdx.x;
    if (i < E) {
        if (ntype[src[i]] == 2) rank[i] = atomicAdd(&deg[dst[i]], 1);
        else                    rank[i] = -1;
        return;
    }
    i -= E;
    if (i < N) { tflag[i] = (ntype[i] == 2) ? 1 : 0; return; }
    i -= N;
    if (i < n4) {
        float4 v = ((const float4*)nf)[i];
        ushort4 o;
        o.x = f2b(v.x); o.y = f2b(v.y); o.z = f2b(v.z); o.w = f2b(v.w);
        ((ushort4*)hb0)[i] = o;
        return;
    }
    int j = i - n4;
    if (j >= 3 * 73728) return;
    int l = j / 73728;
    int idx = j - l * 73728;
    const float* We = (l == 0) ? We0 : (l == 1) ? We1 : We2;
    const float* Wn = (l == 0) ? Wn0 : (l == 1) ? Wn1 : Wn2;
    if (idx < 32768) {
        int sel = idx >> 14, jj = idx & 16383;
        int k = jj >> 7, n = jj & 127;
        WTe[(size_t)l * 32768 + sel * 16384 + n * 128 + k] = f2b(We[sel * 16384 + jj]);
    } else if (idx < 65536) {
        int jj = idx - 32768;
        int k = jj >> 7, n = jj & 127;
        WTn[(size_t)l * 32768 + n * 256 + k] = f2b(Wn[jj]);
    } else {
        int jj = idx - 65536;
        int k = jj >> 7, n = jj & 127;
        WTef[(size_t)l * 8192 + n * 64 + k] = f2b(We[32768 + jj]);
    }
}

// ---------------------------------------------------------------------------
// Scan step 1: per-256-chunk sums.  y=0: deg->bsum AND recvf=(deg>0);
// y=1: tflag->bsum2.
// ---------------------------------------------------------------------------
__global__ __launch_bounds__(256) void k_scan1(
    const int* __restrict__ deg, const int* __restrict__ tflag,
    int* __restrict__ bsum, int* __restrict__ bsum2,
    float* __restrict__ recvf, int n)
{
    __shared__ int s[256];
    const int sel = blockIdx.y;
    const int* v = sel ? tflag : deg;
    int* out = sel ? bsum2 : bsum;
    int i = blockIdx.x * 256 + threadIdx.x;
    int x = (i < n) ? v[i] : 0;
    if (!sel && i < n) recvf[i] = (x > 0) ? 1.0f : 0.0f;
    s[threadIdx.x] = x;
    __syncthreads();
    for (int o = 128; o > 0; o >>= 1) {
        if (threadIdx.x < o) s[threadIdx.x] += s[threadIdx.x + o];
        __syncthreads();
    }
    if (threadIdx.x == 0) out[blockIdx.x] = s[0];
}

// ---------------------------------------------------------------------------
// Scan steps 2+3 merged.  y=0: deg -> cursor (exclusive SEGMENT START),
// total -> cntp.  y=1: tflag -> trank/tlist, total -> tcntp.
// ---------------------------------------------------------------------------
__global__ __launch_bounds__(256) void k_scan23(
    const int* __restrict__ deg, const int* __restrict__ tflag,
    const int* __restrict__ bsum, const int* __restrict__ bsum2,
    int* __restrict__ cursor, int* __restrict__ trank,
    int* __restrict__ tlist, int* __restrict__ cntp, int* __restrict__ tcntp,
    int n, int nb)
{
    __shared__ int bscan[256];
    __shared__ int s[256];
    const int sel = blockIdx.y;
    const int* v = sel ? tflag : deg;
    const int* bs = sel ? bsum2 : bsum;
    const int t = threadIdx.x;

    int bv = (t < nb) ? bs[t] : 0;
    bscan[t] = bv;
    __syncthreads();
    for (int o = 1; o < 256; o <<= 1) {
        int x = (t >= o) ? bscan[t - o] : 0;
        __syncthreads();
        bscan[t] += x;
        __syncthreads();
    }
    const int base  = (blockIdx.x > 0) ? bscan[blockIdx.x - 1] : 0;
    const int total = bscan[nb - 1];

    int i = blockIdx.x * 256 + t;
    int x = (i < n) ? v[i] : 0;
    s[t] = x;
    __syncthreads();
    for (int o = 1; o < 256; o <<= 1) {
        int y = (t >= o) ? s[t - o] : 0;
        __syncthreads();
        s[t] += y;
        __syncthreads();
    }
    if (i < n) {
        int off = base + s[t] - x;
        if (sel) {
            trank[i] = off;
            if (x) tlist[off] = i;
        } else {
            cursor[i] = off;
        }
    }
    if (blockIdx.x == 0 && t == 0) *(sel ? tcntp : cntp) = total;
}

// ---------------------------------------------------------------------------
// Scatter active edges into dst-sorted order — NO atomics: position =
// cursor[dst] (segment start) + rank (from init's histogram).
// ---------------------------------------------------------------------------
__global__ __launch_bounds__(256) void k_scatter_pos(
    const int* __restrict__ src, const int* __restrict__ dst,
    const int* __restrict__ rank, const int* __restrict__ trank,
    const int* __restrict__ cursor, int2* __restrict__ esPair, int E)
{
    int e = blockIdx.x * 256 + threadIdx.x;
    if (e < E) {
        int r = rank[e];
        if (r >= 0) {
            int p = cursor[dst[e]] + r;
            esPair[p] = make_int2(e, trank[src[e]]);
        }
    }
}

// ---------------------------------------------------------------------------
// efgather + layer-0 msg fused: per 64-edge tile, gather+convert ef rows into
// LDS Et (also streamed to efS for layers 1/2), then MFMA msg for layer 0
// straight from Et.  Grid-stride over cnt/64 tiles.
// ---------------------------------------------------------------------------
__global__ __launch_bounds__(256) void k_efmsg(
    const float* __restrict__ ef, const int2* __restrict__ esPair,
    const int* __restrict__ cntp, u16* __restrict__ efS,
    const u16* __restrict__ WTef0, u16* __restrict__ msgS)
{
    __shared__ u16 Et[64][72];
    __shared__ u16 Ms[64][136];
    const int cnt = *cntp;
    const int t = threadIdx.x;
    const int w = t >> 6, lane = t & 63;
    const int lo = lane & 15, q = lane >> 4;
    const int ei = w * 16 + lo;

    for (int tile = blockIdx.x; tile * EPB < cnt; tile += gridDim.x) {
        const int b0 = tile * EPB;
        #pragma unroll
        for (int pz = 0; pz < 4; ++pz) {         // 1024 chunks = 64 edges x 16
            int idx = t + pz * 256;
            int edge = idx >> 4, f4 = idx & 15;
            int p = b0 + edge;
            ushort4 o = make_ushort4(0, 0, 0, 0);
            if (p < cnt) {
                float4 v = *(const float4*)(ef + (size_t)esPair[p].x * 64 + f4 * 4);
                o.x = f2b(v.x); o.y = f2b(v.y); o.z = f2b(v.z); o.w = f2b(v.w);
                *(ushort4*)(efS + (size_t)p * 64 + f4 * 4) = o;
            }
            *(ushort4*)&Et[edge][f4 * 4] = o;
        }
        __syncthreads();

        f32x4 acc[8] = {};
        #pragma unroll
        for (int kf = 0; kf < 2; ++kf) {
            s16x8 b = *(const s16x8*)&Et[ei][kf * 32 + q * 8];
            #pragma unroll
            for (int mi = 0; mi < 8; ++mi) {
                s16x8 a = *(const s16x8*)(WTef0 + (size_t)(mi * 16 + lo) * 64 + kf * 32 + q * 8);
                acc[mi] = __builtin_amdgcn_mfma_f32_16x16x32_bf16(a, b, acc[mi], 0, 0, 0);
            }
        }
        // D mapping: col=lane&15 (edge), row = mi*16 + q*4 + r (feature n)
        #pragma unroll
        for (int mi = 0; mi < 8; ++mi) {
            ushort4 o;
            o.x = f2b(acc[mi][0]); o.y = f2b(acc[mi][1]);
            o.z = f2b(acc[mi][2]); o.w = f2b(acc[mi][3]);
            *(ushort4*)&Ms[ei][mi * 16 + q * 4] = o;
        }
        __syncthreads();
        #pragma unroll
        for (int pz = 0; pz < 4; ++pz) {
            int idx = t + pz * 256;
            int rrow = idx >> 4, c8 = idx & 15;
            int pp = b0 + rrow;
            if (pp < cnt)
                *(int4*)(msgS + (size_t)pp * 128 + c8 * 8) = *(const int4*)&Ms[rrow][c8 * 8];
        }
        __syncthreads();                         // Et/Ms reuse guard
    }
}

// ---------------------------------------------------------------------------
// Pure T GEMM: blocks [0, nT64) = Tsrc-half (task ranks), [nT64, 2*nT64) =
// Tdst-half (all nodes).  64x128 tile, K=128.
// ---------------------------------------------------------------------------
__global__ __launch_bounds__(256) void k_T2(
    const u16* __restrict__ A, const u16* __restrict__ WTe_l,
    u16* __restrict__ Tsrc, u16* __restrict__ Tdst,
    const int* __restrict__ tlist, const int* __restrict__ tcntp,
    int Nfull, int nT64)
{
    __shared__ u16 As[64][72];
    __shared__ u16 Bs[128][72];
    const int t = threadIdx.x;
    const int bx = blockIdx.x;
    const int w = t >> 6, lane = t & 63;
    const int lo = lane & 15, q = lane >> 4;
    const int sel = (bx >= nT64) ? 1 : 0;
    const int M = sel ? Nfull : *tcntp;
    const int m0 = (bx - sel * nT64) * 64;
    if (m0 >= M) return;
    const u16* WT = WTe_l + sel * 16384;
    u16* T = sel ? Tdst : Tsrc;
    const int wm = w >> 1, wn = w & 1;
    f32x4 acc[2][4] = {};

    for (int kt = 0; kt < 128; kt += 64) {
        #pragma unroll
        for (int p = 0; p < 2; ++p) {            // A: 512 int4 chunks
            int c = t + p * 256;
            int row = c >> 3, k8 = c & 7;
            int gm = m0 + row;
            int4 va = make_int4(0, 0, 0, 0);
            if (gm < M) {
                int arow = sel ? gm : tlist[gm];
                va = *(const int4*)(A + (size_t)arow * 128 + kt + k8 * 8);
            }
            *(int4*)&As[row][k8 * 8] = va;
        }
        #pragma unroll
        for (int p = 0; p < 4; ++p) {            // B: 1024 int4 chunks
            int c = t + p * 256;
            int row = c >> 3, k8 = c & 7;
            *(int4*)&Bs[row][k8 * 8] =
                *(const int4*)(WT + (size_t)row * 128 + kt + k8 * 8);
        }
        __syncthreads();
        #pragma unroll
        for (int kf = 0; kf < 2; ++kf) {
            s16x8 a[2], b[4];
            #pragma unroll
            for (int mi = 0; mi < 2; ++mi)
                a[mi] = *(const s16x8*)&As[wm * 32 + mi * 16 + lo][kf * 32 + q * 8];
            #pragma unroll
            for (int ni = 0; ni < 4; ++ni)
                b[ni] = *(const s16x8*)&Bs[wn * 64 + ni * 16 + lo][kf * 32 + q * 8];
            #pragma unroll
            for (int mi = 0; mi < 2; ++mi)
                #pragma unroll
                for (int ni = 0; ni < 4; ++ni)
                    acc[mi][ni] = __builtin_amdgcn_mfma_f32_16x16x32_bf16(
                        a[mi], b[ni], acc[mi][ni], 0, 0, 0);
        }
        __syncthreads();
    }
    #pragma unroll
    for (int mi = 0; mi < 2; ++mi) {
        #pragma unroll
        for (int r = 0; r < 4; ++r) {
            int gm = m0 + wm * 32 + mi * 16 + q * 4 + r;
            if (gm < M) {
                #pragma unroll
                for (int ni = 0; ni < 4; ++ni)
                    T[(size_t)gm * 128 + wn * 64 + ni * 16 + lo] = f2b(acc[mi][ni][r]);
            }
        }
    }
}

// ---------------------------------------------------------------------------
// CSR segmented reduce: one wave per dst node, NO atomics, plain bf16 store.
// cursor[d] = segment START; end = start + deg.
// ---------------------------------------------------------------------------
__global__ __launch_bounds__(256) void k_reduce(
    const u16* __restrict__ msgS, const u16* __restrict__ Tsrc,
    const u16* __restrict__ Tdst, const int2* __restrict__ esPair,
    const int* __restrict__ deg, const int* __restrict__ segStart,
    u16* __restrict__ redb, int N)
{
    const int w = threadIdx.x >> 6, lane = threadIdx.x & 63;
    const int d = blockIdx.x * 4 + w;
    if (d >= N) return;
    const int dg = deg[d];
    if (dg == 0) return;                 // recv=0 masks these rows downstream
    const int beg = segStart[d], end = beg + dg;

    unsigned td = *(const unsigned*)(Tdst + (size_t)d * 128 + lane * 2);
    const float td0 = b2f((u16)(td & 0xffff)), td1 = b2f((u16)(td >> 16));
    float a0 = 0.f, a1 = 0.f;
    for (int i = beg; i < end; ++i) {
        int s = esPair[i].y;             // uniform across wave -> broadcast
        unsigned m  = *(const unsigned*)(msgS + (size_t)i * 128 + lane * 2);
        unsigned ts = *(const unsigned*)(Tsrc + (size_t)s * 128 + lane * 2);
        a0 += leaky(b2f((u16)(m & 0xffff)) + b2f((u16)(ts & 0xffff)) + td0);
        a1 += leaky(b2f((u16)(m >> 16))    + b2f((u16)(ts >> 16))    + td1);
    }
    unsigned out = (unsigned)f2b(a0) | ((unsigned)f2b(a1) << 16);
    *(unsigned*)(redb + (size_t)d * 128 + lane * 2) = out;
}

// ---------------------------------------------------------------------------
// Node kernel + NEXT layer's msg tiles (msg is h-independent):
// blocks [0, nT64) = out = leaky([H | R] @ Wn) * recv  (64x128, K=256);
// blocks [nT64, nT64+MSGB) = msg tiles for layer l+1 (grid-stride), only
// when hasMsg (l < 2).  Fills the under-occupied GEMM dispatch.
// ---------------------------------------------------------------------------
__global__ __launch_bounds__(256) void k_node(
    const u16* __restrict__ H, const u16* __restrict__ R,
    const u16* __restrict__ WT, const float* __restrict__ recvf,
    u16* __restrict__ O16, float* __restrict__ O32, int fin, int M,
    const u16* __restrict__ efS, const u16* __restrict__ WTefN,
    const int* __restrict__ cntp, u16* __restrict__ msgS, int nT64)
{
    __shared__ u16 sh[64 * 72 + 128 * 72];       // GEMM: As|Bs.  msg: Ms.
    const int t = threadIdx.x;
    const int bx = blockIdx.x;
    const int w = t >> 6, lane = t & 63;
    const int lo = lane & 15, q = lane >> 4;

    if (bx < nT64) {
        u16 (*As)[72] = (u16(*)[72])sh;
        u16 (*Bs)[72] = (u16(*)[72])(sh + 64 * 72);
        const int m0 = bx * 64;
        if (m0 >= M) return;
        const int wm = w >> 1, wn = w & 1;
        f32x4 acc[2][4] = {};

        for (int kt = 0; kt < 256; kt += 64) {
            const u16* Ap = (kt < 128) ? (H + kt) : (R + (kt - 128));
            #pragma unroll
            for (int p = 0; p < 2; ++p) {        // A: 512 int4 chunks
                int c = t + p * 256;
                int row = c >> 3, k8 = c & 7;
                int gm = m0 + row;
                int4 va = make_int4(0, 0, 0, 0);
                if (gm < M) va = *(const int4*)(Ap + (size_t)gm * 128 + k8 * 8);
                *(int4*)&As[row][k8 * 8] = va;
            }
            #pragma unroll
            for (int p = 0; p < 4; ++p) {        // B: 1024 int4 chunks
                int c = t + p * 256;
                int row = c >> 3, k8 = c & 7;
                *(int4*)&Bs[row][k8 * 8] =
                    *(const int4*)(WT + (size_t)row * 256 + kt + k8 * 8);
            }
            __syncthreads();
            #pragma unroll
            for (int kf = 0; kf < 2; ++kf) {
                s16x8 a[2], b[4];
                #pragma unroll
                for (int mi = 0; mi < 2; ++mi)
                    a[mi] = *(const s16x8*)&As[wm * 32 + mi * 16 + lo][kf * 32 + q * 8];
                #pragma unroll
                for (int ni = 0; ni < 4; ++ni)
                    b[ni] = *(const s16x8*)&Bs[wn * 64 + ni * 16 + lo][kf * 32 + q * 8];
                #pragma unroll
                for (int mi = 0; mi < 2; ++mi)
                    #pragma unroll
                    for (int ni = 0; ni < 4; ++ni)
                        acc[mi][ni] = __builtin_amdgcn_mfma_f32_16x16x32_bf16(
                            a[mi], b[ni], acc[mi][ni], 0, 0, 0);
            }
            __syncthreads();
        }
        #pragma unroll
        for (int mi = 0; mi < 2; ++mi) {
            #pragma unroll
            for (int r = 0; r < 4; ++r) {
                int gm = m0 + wm * 32 + mi * 16 + q * 4 + r;
                if (gm < M) {
                    float rv = recvf[gm];
                    #pragma unroll
                    for (int ni = 0; ni < 4; ++ni) {
                        float val = leaky(acc[mi][ni][r]) * rv;
                        size_t o = (size_t)gm * 128 + wn * 64 + ni * 16 + lo;
                        if (fin) O32[o] = val;
                        else     O16[o] = f2b(val);
                    }
                }
            }
        }
    } else {
        // ---------------- next layer's msg tiles (grid-stride) ----------
        u16 (*Ms)[136] = (u16(*)[136])sh;
        const int cnt = *cntp;
        const int ei = w * 16 + lo;
        for (int tile = bx - nT64; tile * EPB < cnt; tile += MSGB) {
            const int b0 = tile * EPB;
            const int p = b0 + ei;

            f32x4 acc[8] = {};
            #pragma unroll
            for (int kf = 0; kf < 2; ++kf) {
                s16x8 b = {};
                if (p < cnt) b = *(const s16x8*)(efS + (size_t)p * 64 + kf * 32 + q * 8);
                #pragma unroll
                for (int mi = 0; mi < 8; ++mi) {
                    s16x8 a = *(const s16x8*)(WTefN + (size_t)(mi * 16 + lo) * 64 + kf * 32 + q * 8);
                    acc[mi] = __builtin_amdgcn_mfma_f32_16x16x32_bf16(a, b, acc[mi], 0, 0, 0);
                }
            }
            #pragma unroll
            for (int mi = 0; mi < 8; ++mi) {
                ushort4 o;
                o.x = f2b(acc[mi][0]); o.y = f2b(acc[mi][1]);
                o.z = f2b(acc[mi][2]); o.w = f2b(acc[mi][3]);
                *(ushort4*)&Ms[ei][mi * 16 + q * 4] = o;
            }
            __syncthreads();
            #pragma unroll
            for (int pz = 0; pz < 4; ++pz) {
                int idx = t + pz * 256;
                int rrow = idx >> 4, c8 = idx & 15;
                int pp = b0 + rrow;
                if (pp < cnt)
                    *(int4*)(msgS + (size_t)pp * 128 + c8 * 8) = *(const int4*)&Ms[rrow][c8 * 8];
            }
            __syncthreads();                     // Ms reuse guard
        }
    }
}

// ---------------------------------------------------------------------------
extern "C" void kernel_launch(void* const* d_in, const int* in_sizes, int n_in,
                              void* d_out, int out_size, void* d_ws, size_t ws_size,
                              hipStream_t stream)
{
    const float* nf    = (const float*)d_in[0];
    const float* ef    = (const float*)d_in[1];
    const int*   src   = (const int*)d_in[2];
    const int*   dst   = (const int*)d_in[3];
    const int*   ntype = (const int*)d_in[4];
    const float* We[3] = {(const float*)d_in[5], (const float*)d_in[7], (const float*)d_in[9]};
    const float* Wn[3] = {(const float*)d_in[6], (const float*)d_in[8], (const float*)d_in[10]};

    const int N = in_sizes[0] / 128;
    const int E = in_sizes[1] / 64;

    u16* Tsrc = (u16*)d_ws;                        // N*128 (only *tcnt used)
    u16* Tdst = Tsrc + (size_t)N * 128;            // N*128
    u16* hb0  = Tdst + (size_t)N * 128;            // N*128
    u16* hb1  = hb0 + (size_t)N * 128;             // N*128
    u16* redb = hb1 + (size_t)N * 128;             // N*128 bf16
    u16* WTe  = redb + (size_t)N * 128;            // 3*32768
    u16* WTn  = WTe + 3 * 32768;                   // 3*32768
    u16* WTef = WTn + 3 * 32768;                   // 3*8192
    u16* efS  = WTef + 3 * 8192;                   // E*64 (only cnt*64 used)
    u16* msgS = efS + (size_t)E * 64;              // E*128 (only cnt*128 used)
    float* recvf = (float*)(msgS + (size_t)E * 128); // N
    int* deg    = (int*)(recvf + N);               // N (memset)
    int* cursor = deg + N;                         // N (segment START, immutable)
    int* tflag  = cursor + N;                      // N
    int* trank  = tflag + N;                       // N
    int* tlist  = trank + N;                       // N
    int* bsum   = tlist + N;                       // 256
    int* bsum2  = bsum + 256;                      // 256
    int* cntp   = bsum2 + 256;                     // 1 (+pad)
    int* tcntp  = cntp + 4;                        // 1 (+pad)
    int2* esPair = (int2*)(tcntp + 4);             // E int2
    int* rank   = (int*)(esPair + E);              // E ints

    const int nb  = (N + 255) / 256;               // 196 <= 256 ok
    const int gEb = (E + 255) / 256;
    const int n4  = N * 128 / 4;
    const int nT64 = (N + 63) / 64;
    const int initWork = E + N + n4 + 3 * 73728;

    hipMemsetAsync(deg, 0, (size_t)N * sizeof(int), stream);
    k_init<<<(initWork + 255) / 256, 256, 0, stream>>>(
        src, dst, ntype, deg, tflag, rank, nf, hb0, n4,
        We[0], We[1], We[2], Wn[0], Wn[1], Wn[2], WTe, WTn, WTef, E, N);
    k_scan1<<<dim3(nb, 2), 256, 0, stream>>>(deg, tflag, bsum, bsum2, recvf, N);
    k_scan23<<<dim3(nb, 2), 256, 0, stream>>>(deg, tflag, bsum, bsum2,
                                              cursor, trank, tlist, cntp, tcntp, N, nb);
    k_scatter_pos<<<gEb, 256, 0, stream>>>(src, dst, rank, trank, cursor, esPair, E);
    k_efmsg<<<2048, 256, 0, stream>>>(ef, esPair, cntp, efS, WTef, msgS);

    int gR = (N + 3) / 4;

    const u16* hIn[3]  = {hb0, hb1, hb0};
    u16*       hOut[3] = {hb1, hb0, hb1};
    for (int l = 0; l < 3; ++l) {
        int fin = (l == 2);
        int hasMsg = (l < 2);
        k_T2<<<2 * nT64, 256, 0, stream>>>(hIn[l], WTe + (size_t)l * 32768,
                                           Tsrc, Tdst, tlist, tcntp, N, nT64);
        k_reduce<<<gR, 256, 0, stream>>>(msgS, Tsrc, Tdst, esPair, deg, cursor, redb, N);
        k_node<<<nT64 + (hasMsg ? MSGB : 0), 256, 0, stream>>>(
            hIn[l], redb, WTn + (size_t)l * 32768, recvf, hOut[l], (float*)d_out, fin, N,
            efS, WTef + (size_t)(l + 1) * 8192, cntp, msgS, nT64);
    }
}